// Round 2
// baseline (812.063 us; speedup 1.0000x reference)
//
#include <hip/hip_runtime.h>

// GCN 2-layer: x[N,16] @ W1 -> norm-scatter -> +b1, relu -> @ W2 -> norm-scatter -> +b2
// norm trick: g = dis * (h @ W); out[v] = dis[v] * (sum_{edges u->v} g[u] + g[v]) + b
// NOTE: harness delivers integer inputs as int32 (edge_index is const int*).

static constexpr int F0 = 16;
static constexpr int F1 = 32;
static constexpr int F2 = 2;

__global__ void k_count(const int* __restrict__ dst,
                        unsigned int* __restrict__ cnt, int E) {
    int i = blockIdx.x * blockDim.x + threadIdx.x;
    if (i < E) atomicAdd(&cnt[dst[i]], 1u);
}

__global__ void k_dis(const unsigned int* __restrict__ cnt,
                      float* __restrict__ dis, int N) {
    int i = blockIdx.x * blockDim.x + threadIdx.x;
    if (i < N) dis[i] = rsqrtf((float)(cnt[i] + 1u));  // +1 = self loop
}

// g1[i,:] = dis[i] * (x[i,:] @ W1)   (W1: 16x32 in LDS)
__global__ void k_g1(const float* __restrict__ x, const float* __restrict__ W1,
                     const float* __restrict__ dis, float* __restrict__ g1, int N) {
    __shared__ float w[F0 * F1];
    for (int j = threadIdx.x; j < F0 * F1; j += blockDim.x) w[j] = W1[j];
    __syncthreads();
    int i = blockIdx.x * blockDim.x + threadIdx.x;
    if (i >= N) return;
    float xr[F0];
    const float4* xp = reinterpret_cast<const float4*>(x + (size_t)i * F0);
#pragma unroll
    for (int q = 0; q < F0 / 4; ++q) {
        float4 v = xp[q];
        xr[q * 4 + 0] = v.x; xr[q * 4 + 1] = v.y;
        xr[q * 4 + 2] = v.z; xr[q * 4 + 3] = v.w;
    }
    float d = dis[i];
    float o[F1];
#pragma unroll
    for (int j = 0; j < F1; ++j) o[j] = 0.0f;
#pragma unroll
    for (int k = 0; k < F0; ++k) {
        float xv = xr[k];
#pragma unroll
        for (int j = 0; j < F1; ++j) o[j] = fmaf(xv, w[k * F1 + j], o[j]);
    }
    float4* gp = reinterpret_cast<float4*>(g1 + (size_t)i * F1);
#pragma unroll
    for (int q = 0; q < F1 / 4; ++q) {
        float4 v;
        v.x = d * o[q * 4 + 0]; v.y = d * o[q * 4 + 1];
        v.z = d * o[q * 4 + 2]; v.w = d * o[q * 4 + 3];
        gp[q] = v;
    }
}

// one thread per (edge, feature): acc1[dst, f] += g1[src, f]
__global__ void k_scatter1(const int* __restrict__ src,
                           const int* __restrict__ dst,
                           const float* __restrict__ g1,
                           float* __restrict__ acc1, int E32) {
    int gid = blockIdx.x * blockDim.x + threadIdx.x;
    if (gid >= E32) return;
    int e = gid >> 5;        // F1 = 32 features
    int f = gid & 31;
    int s = src[e];
    int d = dst[e];
    atomicAdd(&acc1[(size_t)d * F1 + f], g1[(size_t)s * F1 + f]);
}

// z = relu(dis*(acc1+g1) + b1); g2 = dis * (z @ W2)   (W2: 32x2)
__global__ void k_g2(const float* __restrict__ acc1, const float* __restrict__ g1,
                     const float* __restrict__ dis, const float* __restrict__ b1,
                     const float* __restrict__ W2, float* __restrict__ g2, int N) {
    __shared__ float w[F1 * F2];
    __shared__ float bb[F1];
    for (int j = threadIdx.x; j < F1 * F2; j += blockDim.x) w[j] = W2[j];
    for (int j = threadIdx.x; j < F1; j += blockDim.x) bb[j] = b1[j];
    __syncthreads();
    int i = blockIdx.x * blockDim.x + threadIdx.x;
    if (i >= N) return;
    float d = dis[i];
    const float4* ap = reinterpret_cast<const float4*>(acc1 + (size_t)i * F1);
    const float4* gp = reinterpret_cast<const float4*>(g1 + (size_t)i * F1);
    float o0 = 0.0f, o1 = 0.0f;
#pragma unroll
    for (int q = 0; q < F1 / 4; ++q) {
        float4 a = ap[q];
        float4 g = gp[q];
        float z[4] = { a.x + g.x, a.y + g.y, a.z + g.z, a.w + g.w };
#pragma unroll
        for (int t = 0; t < 4; ++t) {
            int f = q * 4 + t;
            float r = fmaf(d, z[t], bb[f]);
            r = fmaxf(r, 0.0f);
            o0 = fmaf(r, w[f * F2 + 0], o0);
            o1 = fmaf(r, w[f * F2 + 1], o1);
        }
    }
    g2[(size_t)i * F2 + 0] = d * o0;
    g2[(size_t)i * F2 + 1] = d * o1;
}

// one thread per edge: acc2[dst, 0:2] += g2[src, 0:2]
__global__ void k_scatter2(const int* __restrict__ src,
                           const int* __restrict__ dst,
                           const float* __restrict__ g2,
                           float* __restrict__ acc2, int E) {
    int e = blockIdx.x * blockDim.x + threadIdx.x;
    if (e >= E) return;
    int s = src[e];
    int d = dst[e];
    atomicAdd(&acc2[(size_t)d * F2 + 0], g2[(size_t)s * F2 + 0]);
    atomicAdd(&acc2[(size_t)d * F2 + 1], g2[(size_t)s * F2 + 1]);
}

// out = dis*(acc2 + g2) + b2
__global__ void k_out(const float* __restrict__ acc2, const float* __restrict__ g2,
                      const float* __restrict__ dis, const float* __restrict__ b2,
                      float* __restrict__ out, int N2) {
    int i = blockIdx.x * blockDim.x + threadIdx.x;
    if (i >= N2) return;
    int v = i >> 1;   // F2 = 2
    int f = i & 1;
    out[i] = fmaf(dis[v], acc2[i] + g2[i], b2[f]);
}

extern "C" void kernel_launch(void* const* d_in, const int* in_sizes, int n_in,
                              void* d_out, int out_size, void* d_ws, size_t ws_size,
                              hipStream_t stream) {
    const float* x  = (const float*)d_in[0];
    const int* ei   = (const int*)d_in[1];     // int32 per harness conversion
    const float* W1 = (const float*)d_in[2];
    const float* b1 = (const float*)d_in[3];
    const float* W2 = (const float*)d_in[4];
    const float* b2 = (const float*)d_in[5];
    float* out = (float*)d_out;

    const int N = in_sizes[0] / F0;          // 100000
    const int E = in_sizes[1] / 2;           // 3200000
    const int* src = ei;
    const int* dst = ei + E;

    // workspace layout (floats)
    float* ws = (float*)d_ws;
    unsigned int* cnt = (unsigned int*)ws;          // N
    float* dis  = ws + N;                           // N
    float* g1   = ws + 2 * (size_t)N;               // 32N
    float* acc1 = ws + 34 * (size_t)N;              // 32N
    float* g2   = ws + 66 * (size_t)N;              // 2N
    float* acc2 = ws + 68 * (size_t)N;              // 2N
    // total 70N floats = 28 MB

    hipMemsetAsync(d_ws, 0, (size_t)70 * N * sizeof(float), stream);

    const int B = 256;
    k_count<<<(E + B - 1) / B, B, 0, stream>>>(dst, cnt, E);
    k_dis<<<(N + B - 1) / B, B, 0, stream>>>(cnt, dis, N);
    k_g1<<<(N + B - 1) / B, B, 0, stream>>>(x, W1, dis, g1, N);
    const int E32 = E * F1;
    k_scatter1<<<(E32 + B - 1) / B, B, 0, stream>>>(src, dst, g1, acc1, E32);
    k_g2<<<(N + B - 1) / B, B, 0, stream>>>(acc1, g1, dis, b1, W2, g2, N);
    k_scatter2<<<(E + B - 1) / B, B, 0, stream>>>(src, dst, g2, acc2, E);
    k_out<<<(N * F2 + B - 1) / B, B, 0, stream>>>(acc2, g2, dis, b2, out, N * F2);
}

// Round 3
// 401.072 us; speedup vs baseline: 2.0247x; 2.0247x over previous
//
#include <hip/hip_runtime.h>

// GCN 2-layer via per-call CSR (counting sort by dst) + gather-sum.
// norm trick: g = dis * (h @ W); out[v] = dis[v]*(sum_{u->v} g[u] + g[v]) + b
// edge_index arrives as int32 (harness converts integer inputs).

static constexpr int F0 = 16;
static constexpr int F1 = 32;
static constexpr int F2 = 2;
static constexpr int SCAN_B = 256;

__global__ void k_count(const int* __restrict__ dst,
                        unsigned int* __restrict__ cnt, int E) {
    int i = blockIdx.x * blockDim.x + threadIdx.x;
    if (i < E) atomicAdd(&cnt[dst[i]], 1u);
}

__global__ void k_dis(const unsigned int* __restrict__ cnt,
                      float* __restrict__ dis, int N) {
    int i = blockIdx.x * blockDim.x + threadIdx.x;
    if (i < N) dis[i] = rsqrtf((float)(cnt[i] + 1u));  // +1 self loop
}

// block-local exclusive scan of cnt -> rowptr, block totals -> partials
__global__ void k_scan_a(const unsigned int* __restrict__ cnt,
                         int* __restrict__ rowptr, int* __restrict__ partials, int N) {
    __shared__ int s[SCAN_B];
    int tid = threadIdx.x;
    int i = blockIdx.x * SCAN_B + tid;
    int v = (i < N) ? (int)cnt[i] : 0;
    s[tid] = v;
    __syncthreads();
    for (int off = 1; off < SCAN_B; off <<= 1) {
        int t = (tid >= off) ? s[tid - off] : 0;
        __syncthreads();
        s[tid] += t;
        __syncthreads();
    }
    if (i < N) rowptr[i] = s[tid] - v;           // exclusive
    if (tid == SCAN_B - 1) partials[blockIdx.x] = s[tid];
}

// single-block exclusive scan of partials (P <= 512)
__global__ void k_scan_b(int* __restrict__ partials, int P) {
    __shared__ int s[512];
    int tid = threadIdx.x;
    int v = (tid < P) ? partials[tid] : 0;
    s[tid] = v;
    __syncthreads();
    for (int off = 1; off < 512; off <<= 1) {
        int t = (tid >= off) ? s[tid - off] : 0;
        __syncthreads();
        s[tid] += t;
        __syncthreads();
    }
    if (tid < P) partials[tid] = s[tid] - v;     // exclusive
}

__global__ void k_scan_c(int* __restrict__ rowptr, const int* __restrict__ partials, int N) {
    int i = blockIdx.x * SCAN_B + threadIdx.x;
    if (i < N) rowptr[i] += partials[blockIdx.x];
}

// bucket edges by dst: esrc[rowptr[d] + fill[d]++] = src[e]
__global__ void k_bucket(const int* __restrict__ src, const int* __restrict__ dst,
                         const int* __restrict__ rowptr, unsigned int* __restrict__ fill,
                         int* __restrict__ esrc, int E) {
    int e = blockIdx.x * blockDim.x + threadIdx.x;
    if (e >= E) return;
    int d = dst[e];
    int pos = rowptr[d] + (int)atomicAdd(&fill[d], 1u);
    esrc[pos] = src[e];
}

// g1[i,:] = dis[i] * (x[i,:] @ W1)
__global__ void k_g1(const float* __restrict__ x, const float* __restrict__ W1,
                     const float* __restrict__ dis, float* __restrict__ g1, int N) {
    __shared__ float w[F0 * F1];
    for (int j = threadIdx.x; j < F0 * F1; j += blockDim.x) w[j] = W1[j];
    __syncthreads();
    int i = blockIdx.x * blockDim.x + threadIdx.x;
    if (i >= N) return;
    float xr[F0];
    const float4* xp = reinterpret_cast<const float4*>(x + (size_t)i * F0);
#pragma unroll
    for (int q = 0; q < F0 / 4; ++q) {
        float4 v = xp[q];
        xr[q * 4 + 0] = v.x; xr[q * 4 + 1] = v.y;
        xr[q * 4 + 2] = v.z; xr[q * 4 + 3] = v.w;
    }
    float d = dis[i];
    float o[F1];
#pragma unroll
    for (int j = 0; j < F1; ++j) o[j] = 0.0f;
#pragma unroll
    for (int k = 0; k < F0; ++k) {
        float xv = xr[k];
#pragma unroll
        for (int j = 0; j < F1; ++j) o[j] = fmaf(xv, w[k * F1 + j], o[j]);
    }
    float4* gp = reinterpret_cast<float4*>(g1 + (size_t)i * F1);
#pragma unroll
    for (int q = 0; q < F1 / 4; ++q) {
        float4 v;
        v.x = d * o[q * 4 + 0]; v.y = d * o[q * 4 + 1];
        v.z = d * o[q * 4 + 2]; v.w = d * o[q * 4 + 3];
        gp[q] = v;
    }
}

// fused layer1 aggregate + bias + relu + W2 GEMM:
// 8 lanes per node (float4 each). g2[v,:] = dis[v]*(relu(dis[v]*(sum g1[nbr]+g1[v]) + b1) @ W2)
__global__ void k_layer1(const float* __restrict__ g1, const unsigned int* __restrict__ cnt,
                         const int* __restrict__ rowptr, const int* __restrict__ esrc,
                         const float* __restrict__ dis, const float* __restrict__ b1,
                         const float* __restrict__ W2, float* __restrict__ g2, int N) {
    __shared__ float w[F1 * F2];
    __shared__ float bb[F1];
    for (int j = threadIdx.x; j < F1 * F2; j += blockDim.x) w[j] = W2[j];
    for (int j = threadIdx.x; j < F1; j += blockDim.x) bb[j] = b1[j];
    __syncthreads();
    int t = blockIdx.x * blockDim.x + threadIdx.x;
    int v = t >> 3;
    int q = t & 7;
    if (v >= N) return;
    const float4* gbase = reinterpret_cast<const float4*>(g1) + q;
    float4 o = gbase[(size_t)v * 8];     // self loop term g1[v]
    int beg = rowptr[v];
    int end = beg + (int)cnt[v];
    for (int j = beg; j < end; ++j) {
        int s = esrc[j];
        float4 a = gbase[(size_t)s * 8];
        o.x += a.x; o.y += a.y; o.z += a.z; o.w += a.w;
    }
    float d = dis[v];
    float p0 = 0.0f, p1 = 0.0f;
    float oz[4] = { o.x, o.y, o.z, o.w };
#pragma unroll
    for (int u = 0; u < 4; ++u) {
        int f = q * 4 + u;
        float r = fmaxf(fmaf(d, oz[u], bb[f]), 0.0f);
        p0 = fmaf(r, w[f * F2 + 0], p0);
        p1 = fmaf(r, w[f * F2 + 1], p1);
    }
#pragma unroll
    for (int off = 1; off < 8; off <<= 1) {
        p0 += __shfl_xor(p0, off);
        p1 += __shfl_xor(p1, off);
    }
    if (q == 0) {
        g2[(size_t)v * F2 + 0] = d * p0;
        g2[(size_t)v * F2 + 1] = d * p1;
    }
}

// fused layer2 aggregate + output: 4 lanes per node, strided edges
__global__ void k_out2(const float* __restrict__ g2, const unsigned int* __restrict__ cnt,
                       const int* __restrict__ rowptr, const int* __restrict__ esrc,
                       const float* __restrict__ dis, const float* __restrict__ b2,
                       float* __restrict__ out, int N) {
    int t = blockIdx.x * blockDim.x + threadIdx.x;
    int v = t >> 2;
    int l = t & 3;
    if (v >= N) return;
    float o0 = 0.0f, o1 = 0.0f;
    int beg = rowptr[v];
    int end = beg + (int)cnt[v];
    for (int j = beg + l; j < end; j += 4) {
        int s = esrc[j];
        const float2 a = *reinterpret_cast<const float2*>(g2 + (size_t)s * F2);
        o0 += a.x; o1 += a.y;
    }
#pragma unroll
    for (int off = 1; off < 4; off <<= 1) {
        o0 += __shfl_xor(o0, off);
        o1 += __shfl_xor(o1, off);
    }
    if (l == 0) {
        float d = dis[v];
        const float2 self = *reinterpret_cast<const float2*>(g2 + (size_t)v * F2);
        out[(size_t)v * F2 + 0] = fmaf(d, o0 + self.x, b2[0]);
        out[(size_t)v * F2 + 1] = fmaf(d, o1 + self.y, b2[1]);
    }
}

extern "C" void kernel_launch(void* const* d_in, const int* in_sizes, int n_in,
                              void* d_out, int out_size, void* d_ws, size_t ws_size,
                              hipStream_t stream) {
    const float* x  = (const float*)d_in[0];
    const int* ei   = (const int*)d_in[1];
    const float* W1 = (const float*)d_in[2];
    const float* b1 = (const float*)d_in[3];
    const float* W2 = (const float*)d_in[4];
    const float* b2 = (const float*)d_in[5];
    float* out = (float*)d_out;

    const int N = in_sizes[0] / F0;          // 100000
    const int E = in_sizes[1] / 2;           // 3200000
    const int* src = ei;
    const int* dst = ei + E;

    // workspace layout (4-byte units)
    char* ws = (char*)d_ws;
    unsigned int* cnt  = (unsigned int*)ws;                   // N
    unsigned int* fill = cnt + N;                             // N
    int* rowptr        = (int*)(fill + N);                    // N
    float* dis         = (float*)(rowptr + N);                // N
    float* g1          = dis + N;                             // 32N
    float* g2          = g1 + (size_t)32 * N;                 // 2N
    int* esrc          = (int*)(g2 + (size_t)2 * N);          // E
    int* partials      = esrc + E;                            // <=512

    // zero only cnt + fill (contiguous)
    hipMemsetAsync(cnt, 0, (size_t)2 * N * sizeof(int), stream);

    const int B = 256;
    const int nscan = (N + SCAN_B - 1) / SCAN_B;              // 391
    k_count<<<(E + B - 1) / B, B, 0, stream>>>(dst, cnt, E);
    k_dis<<<(N + B - 1) / B, B, 0, stream>>>(cnt, dis, N);
    k_scan_a<<<nscan, SCAN_B, 0, stream>>>(cnt, rowptr, partials, N);
    k_scan_b<<<1, 512, 0, stream>>>(partials, nscan);
    k_scan_c<<<nscan, SCAN_B, 0, stream>>>(rowptr, partials, N);
    k_g1<<<(N + B - 1) / B, B, 0, stream>>>(x, W1, dis, g1, N);
    k_bucket<<<(E + B - 1) / B, B, 0, stream>>>(src, dst, rowptr, fill, esrc, E);
    k_layer1<<<(N * 8 + B - 1) / B, B, 0, stream>>>(g1, cnt, rowptr, esrc, dis, b1, W2, g2, N);
    k_out2<<<(N * 4 + B - 1) / B, B, 0, stream>>>(g2, cnt, rowptr, esrc, dis, b2, out, N);
}

// Round 4
// 237.324 us; speedup vs baseline: 3.4217x; 1.6900x over previous
//
#include <hip/hip_runtime.h>

// GCN 2-layer via two-level counting-sort CSR + gather-sum (no float atomics).
// norm trick: g = dis * (h @ W); out[v] = dis[v]*(sum_{u->v} g[u] + g[v]) + b
// edge_index arrives as int32 (harness converts integer inputs).
//
// Binning: bucket b = dst>>8 (256 nodes per bucket, nb=391 for N=100000).
//   k_bhist: per-block LDS histogram of buckets -> global totals (line-padded)
//   k_bscan: exclusive scan of bucket totals -> bucket_base, init bucket_fill
//   k_binA : scatter packed (src<<8 | dst&255) into bucket-contiguous regions
//   k_binB : one block per bucket; LDS node-histogram + scan -> cnt/dis/rstart,
//            then LDS-cursor scatter of src into esrc (node-sorted CSR)

static constexpr int F0 = 16;
static constexpr int F1 = 32;
static constexpr int F2 = 2;
static constexpr int MAXNB = 512;   // max coarse buckets
static constexpr int BPAD  = 16;    // pad global counters to own 64B line
static constexpr int EPB   = 8192;  // edges per k_binA block

__global__ void k_bhist(const int* __restrict__ dst, unsigned int* __restrict__ btot,
                        int E, int nb, int nblocks) {
    __shared__ unsigned int h[MAXNB];
    for (int b = threadIdx.x; b < MAXNB; b += blockDim.x) h[b] = 0;
    __syncthreads();
    for (int e = blockIdx.x * blockDim.x + threadIdx.x; e < E; e += nblocks * blockDim.x)
        atomicAdd(&h[((unsigned)dst[e]) >> 8], 1u);
    __syncthreads();
    for (int b = threadIdx.x; b < nb; b += blockDim.x)
        if (h[b]) atomicAdd(&btot[b * BPAD], h[b]);
}

// single block of MAXNB threads: exclusive scan of bucket totals
__global__ void k_bscan(const unsigned int* __restrict__ btot, int* __restrict__ bbase,
                        unsigned int* __restrict__ bfill, int nb, int E) {
    __shared__ int s[MAXNB];
    int tid = threadIdx.x;
    int v = (tid < nb) ? (int)btot[tid * BPAD] : 0;
    s[tid] = v;
    __syncthreads();
    for (int off = 1; off < MAXNB; off <<= 1) {
        int t = (tid >= off) ? s[tid - off] : 0;
        __syncthreads();
        s[tid] += t;
        __syncthreads();
    }
    if (tid < nb) {
        int ex = s[tid] - v;
        bbase[tid] = ex;
        bfill[tid * BPAD] = (unsigned)ex;
    }
    if (tid == 0) bbase[nb] = E;
}

__global__ void k_binA(const int* __restrict__ src, const int* __restrict__ dst,
                       unsigned int* __restrict__ bfill, unsigned int* __restrict__ pairs,
                       int E, int nb) {
    __shared__ unsigned int h[MAXNB];
    __shared__ unsigned int bs[MAXNB];
    __shared__ unsigned int cur[MAXNB];
    for (int b = threadIdx.x; b < MAXNB; b += blockDim.x) { h[b] = 0; cur[b] = 0; }
    __syncthreads();
    int e0 = blockIdx.x * EPB;
    int e1 = min(e0 + EPB, E);
    for (int e = e0 + (int)threadIdx.x; e < e1; e += blockDim.x)
        atomicAdd(&h[((unsigned)dst[e]) >> 8], 1u);
    __syncthreads();
    for (int b = threadIdx.x; b < nb; b += blockDim.x)
        bs[b] = h[b] ? atomicAdd(&bfill[b * BPAD], h[b]) : 0u;
    __syncthreads();
    for (int e = e0 + (int)threadIdx.x; e < e1; e += blockDim.x) {
        unsigned d = (unsigned)dst[e];
        unsigned b = d >> 8;
        unsigned off = atomicAdd(&cur[b], 1u);
        pairs[bs[b] + off] = (((unsigned)src[e]) << 8) | (d & 255u);
    }
}

// one block (256 threads) per bucket
__global__ void k_binB(const unsigned int* __restrict__ pairs, const int* __restrict__ bbase,
                       int* __restrict__ cnt, float* __restrict__ dis,
                       int* __restrict__ rstart, int* __restrict__ esrc, int N) {
    __shared__ unsigned int h[256];
    __shared__ int sc[256];
    __shared__ unsigned int cur[256];
    int tid = threadIdx.x;
    int b = blockIdx.x;
    int node0 = b << 8;
    h[tid] = 0;
    cur[tid] = 0;
    __syncthreads();
    int r0 = bbase[b], r1 = bbase[b + 1];
    for (int i = r0 + tid; i < r1; i += 256)
        atomicAdd(&h[pairs[i] & 255u], 1u);
    __syncthreads();
    int v = (int)h[tid];
    sc[tid] = v;
    __syncthreads();
    for (int off = 1; off < 256; off <<= 1) {
        int t = (tid >= off) ? sc[tid - off] : 0;
        __syncthreads();
        sc[tid] += t;
        __syncthreads();
    }
    int ex = sc[tid] - v;          // exclusive scan value
    __syncthreads();
    sc[tid] = ex;
    __syncthreads();
    int node = node0 + tid;
    if (node < N) {
        cnt[node] = v;
        dis[node] = rsqrtf((float)(v + 1));
        rstart[node] = r0 + ex;
    }
    for (int i = r0 + tid; i < r1; i += 256) {
        unsigned p = pairs[i];
        unsigned l = p & 255u;
        unsigned off = atomicAdd(&cur[l], 1u);
        esrc[r0 + sc[l] + (int)off] = (int)(p >> 8);
    }
}

// g1[i,:] = dis[i] * (x[i,:] @ W1)
__global__ void k_g1(const float* __restrict__ x, const float* __restrict__ W1,
                     const float* __restrict__ dis, float* __restrict__ g1, int N) {
    __shared__ float w[F0 * F1];
    for (int j = threadIdx.x; j < F0 * F1; j += blockDim.x) w[j] = W1[j];
    __syncthreads();
    int i = blockIdx.x * blockDim.x + threadIdx.x;
    if (i >= N) return;
    float xr[F0];
    const float4* xp = reinterpret_cast<const float4*>(x + (size_t)i * F0);
#pragma unroll
    for (int q = 0; q < F0 / 4; ++q) {
        float4 v = xp[q];
        xr[q * 4 + 0] = v.x; xr[q * 4 + 1] = v.y;
        xr[q * 4 + 2] = v.z; xr[q * 4 + 3] = v.w;
    }
    float d = dis[i];
    float o[F1];
#pragma unroll
    for (int j = 0; j < F1; ++j) o[j] = 0.0f;
#pragma unroll
    for (int k = 0; k < F0; ++k) {
        float xv = xr[k];
#pragma unroll
        for (int j = 0; j < F1; ++j) o[j] = fmaf(xv, w[k * F1 + j], o[j]);
    }
    float4* gp = reinterpret_cast<float4*>(g1 + (size_t)i * F1);
#pragma unroll
    for (int q = 0; q < F1 / 4; ++q) {
        float4 v;
        v.x = d * o[q * 4 + 0]; v.y = d * o[q * 4 + 1];
        v.z = d * o[q * 4 + 2]; v.w = d * o[q * 4 + 3];
        gp[q] = v;
    }
}

// fused layer1 aggregate + bias + relu + W2 GEMM; 8 lanes per node (float4 each)
__global__ void k_layer1(const float* __restrict__ g1, const int* __restrict__ cnt,
                         const int* __restrict__ rstart, const int* __restrict__ esrc,
                         const float* __restrict__ dis, const float* __restrict__ b1,
                         const float* __restrict__ W2, float* __restrict__ g2, int N) {
    __shared__ float w[F1 * F2];
    __shared__ float bb[F1];
    for (int j = threadIdx.x; j < F1 * F2; j += blockDim.x) w[j] = W2[j];
    for (int j = threadIdx.x; j < F1; j += blockDim.x) bb[j] = b1[j];
    __syncthreads();
    int t = blockIdx.x * blockDim.x + threadIdx.x;
    int v = t >> 3;
    int q = t & 7;
    if (v >= N) return;
    const float4* gbase = reinterpret_cast<const float4*>(g1) + q;
    float4 o = gbase[(size_t)v * 8];     // self loop term g1[v]
    int beg = rstart[v];
    int end = beg + cnt[v];
    for (int j = beg; j < end; ++j) {
        int s = esrc[j];
        float4 a = gbase[(size_t)s * 8];
        o.x += a.x; o.y += a.y; o.z += a.z; o.w += a.w;
    }
    float d = dis[v];
    float p0 = 0.0f, p1 = 0.0f;
    float oz[4] = { o.x, o.y, o.z, o.w };
#pragma unroll
    for (int u = 0; u < 4; ++u) {
        int f = q * 4 + u;
        float r = fmaxf(fmaf(d, oz[u], bb[f]), 0.0f);
        p0 = fmaf(r, w[f * F2 + 0], p0);
        p1 = fmaf(r, w[f * F2 + 1], p1);
    }
#pragma unroll
    for (int off = 1; off < 8; off <<= 1) {
        p0 += __shfl_xor(p0, off);
        p1 += __shfl_xor(p1, off);
    }
    if (q == 0) {
        g2[(size_t)v * F2 + 0] = d * p0;
        g2[(size_t)v * F2 + 1] = d * p1;
    }
}

// fused layer2 aggregate + output: 4 lanes per node, strided edges
__global__ void k_out2(const float* __restrict__ g2, const int* __restrict__ cnt,
                       const int* __restrict__ rstart, const int* __restrict__ esrc,
                       const float* __restrict__ dis, const float* __restrict__ b2,
                       float* __restrict__ out, int N) {
    int t = blockIdx.x * blockDim.x + threadIdx.x;
    int v = t >> 2;
    int l = t & 3;
    if (v >= N) return;
    float o0 = 0.0f, o1 = 0.0f;
    int beg = rstart[v];
    int end = beg + cnt[v];
    for (int j = beg + l; j < end; j += 4) {
        int s = esrc[j];
        const float2 a = *reinterpret_cast<const float2*>(g2 + (size_t)s * F2);
        o0 += a.x; o1 += a.y;
    }
#pragma unroll
    for (int off = 1; off < 4; off <<= 1) {
        o0 += __shfl_xor(o0, off);
        o1 += __shfl_xor(o1, off);
    }
    if (l == 0) {
        float d = dis[v];
        const float2 self = *reinterpret_cast<const float2*>(g2 + (size_t)v * F2);
        out[(size_t)v * F2 + 0] = fmaf(d, o0 + self.x, b2[0]);
        out[(size_t)v * F2 + 1] = fmaf(d, o1 + self.y, b2[1]);
    }
}

extern "C" void kernel_launch(void* const* d_in, const int* in_sizes, int n_in,
                              void* d_out, int out_size, void* d_ws, size_t ws_size,
                              hipStream_t stream) {
    const float* x  = (const float*)d_in[0];
    const int* ei   = (const int*)d_in[1];
    const float* W1 = (const float*)d_in[2];
    const float* b1 = (const float*)d_in[3];
    const float* W2 = (const float*)d_in[4];
    const float* b2 = (const float*)d_in[5];
    float* out = (float*)d_out;

    const int N = in_sizes[0] / F0;          // 100000
    const int E = in_sizes[1] / 2;           // 3200000
    const int* src = ei;
    const int* dst = ei + E;
    const int nb = (N + 255) >> 8;           // 391 buckets

    // workspace layout (4-byte units)
    char* wsb = (char*)d_ws;
    unsigned int* btot  = (unsigned int*)wsb;                 // MAXNB*BPAD
    unsigned int* bfill = btot + MAXNB * BPAD;                // MAXNB*BPAD
    int* bbase          = (int*)(bfill + MAXNB * BPAD);       // MAXNB+1
    int* cnt            = bbase + MAXNB + 1;                  // N
    float* dis          = (float*)(cnt + N);                  // N
    int* rstart         = (int*)(dis + N);                    // N
    unsigned int* pairs = (unsigned int*)(rstart + N);        // E
    int* esrc           = (int*)(pairs + E);                  // E
    float* g1           = (float*)(esrc + E);                 // 32N
    float* g2           = g1 + (size_t)32 * N;                // 2N
    // total ~ (3N + 2E + 34N + 17k) * 4B  ~= 40.5 MB

    hipMemsetAsync(btot, 0, (size_t)MAXNB * BPAD * sizeof(int), stream);

    const int B = 256;
    k_bhist<<<nb, B, 0, stream>>>(dst, btot, E, nb, nb);
    k_bscan<<<1, MAXNB, 0, stream>>>(btot, bbase, bfill, nb, E);
    k_binA<<<(E + EPB - 1) / EPB, B, 0, stream>>>(src, dst, bfill, pairs, E, nb);
    k_binB<<<nb, B, 0, stream>>>(pairs, bbase, cnt, dis, rstart, esrc, N);
    k_g1<<<(N + B - 1) / B, B, 0, stream>>>(x, W1, dis, g1, N);
    k_layer1<<<(N * 8 + B - 1) / B, B, 0, stream>>>(g1, cnt, rstart, esrc, dis, b1, W2, g2, N);
    k_out2<<<(N * 4 + B - 1) / B, B, 0, stream>>>(g2, cnt, rstart, esrc, dis, b2, out, N);
}

// Round 5
// 201.138 us; speedup vs baseline: 4.0373x; 1.1799x over previous
//
#include <hip/hip_runtime.h>

// GCN 2-layer via two-level counting-sort CSR + gather-sum (no float atomics).
// norm trick: g = dis * (h @ W); out[v] = dis[v]*(sum_{u->v} g[u] + g[v]) + b
// g1 stored as bf16 (RNE) -> 64B row = 1 cache line per edge gather.

static constexpr int F0 = 16;
static constexpr int F1 = 32;
static constexpr int F2 = 2;
static constexpr int MAXNB = 512;   // max coarse buckets
static constexpr int BPAD  = 16;    // pad global counters to own 64B line
static constexpr int EPB   = 8192;  // edges per k_binA block

__device__ inline unsigned short f2bf(float f) {
    unsigned u = __float_as_uint(f);
    unsigned r = (u + 0x7fffu + ((u >> 16) & 1u)) >> 16;   // RNE
    return (unsigned short)r;
}
__device__ inline float bf2f(unsigned short b) {
    return __uint_as_float(((unsigned)b) << 16);
}

__global__ void k_bhist(const int* __restrict__ dst, unsigned int* __restrict__ btot,
                        int E, int nb, int nblocks) {
    __shared__ unsigned int h[MAXNB];
    for (int b = threadIdx.x; b < MAXNB; b += blockDim.x) h[b] = 0;
    __syncthreads();
    for (int e = blockIdx.x * blockDim.x + threadIdx.x; e < E; e += nblocks * blockDim.x)
        atomicAdd(&h[((unsigned)dst[e]) >> 8], 1u);
    __syncthreads();
    for (int b = threadIdx.x; b < nb; b += blockDim.x)
        if (h[b]) atomicAdd(&btot[b * BPAD], h[b]);
}

// single block of MAXNB threads: exclusive scan of bucket totals
__global__ void k_bscan(const unsigned int* __restrict__ btot, int* __restrict__ bbase,
                        unsigned int* __restrict__ bfill, int nb, int E) {
    __shared__ int s[MAXNB];
    int tid = threadIdx.x;
    int v = (tid < nb) ? (int)btot[tid * BPAD] : 0;
    s[tid] = v;
    __syncthreads();
    for (int off = 1; off < MAXNB; off <<= 1) {
        int t = (tid >= off) ? s[tid - off] : 0;
        __syncthreads();
        s[tid] += t;
        __syncthreads();
    }
    if (tid < nb) {
        int ex = s[tid] - v;
        bbase[tid] = ex;
        bfill[tid * BPAD] = (unsigned)ex;
    }
    if (tid == 0) bbase[nb] = E;
}

__global__ void k_binA(const int* __restrict__ src, const int* __restrict__ dst,
                       unsigned int* __restrict__ bfill, unsigned int* __restrict__ pairs,
                       int E, int nb) {
    __shared__ unsigned int h[MAXNB];
    __shared__ unsigned int bs[MAXNB];
    __shared__ unsigned int cur[MAXNB];
    for (int b = threadIdx.x; b < MAXNB; b += blockDim.x) { h[b] = 0; cur[b] = 0; }
    __syncthreads();
    int e0 = blockIdx.x * EPB;
    int e1 = min(e0 + EPB, E);
    for (int e = e0 + (int)threadIdx.x; e < e1; e += blockDim.x)
        atomicAdd(&h[((unsigned)dst[e]) >> 8], 1u);
    __syncthreads();
    for (int b = threadIdx.x; b < nb; b += blockDim.x)
        bs[b] = h[b] ? atomicAdd(&bfill[b * BPAD], h[b]) : 0u;
    __syncthreads();
    for (int e = e0 + (int)threadIdx.x; e < e1; e += blockDim.x) {
        unsigned d = (unsigned)dst[e];
        unsigned b = d >> 8;
        unsigned off = atomicAdd(&cur[b], 1u);
        pairs[bs[b] + off] = (((unsigned)src[e]) << 8) | (d & 255u);
    }
}

// one block (256 threads) per bucket: node hist + scan -> cnt/dis/rstart, scatter esrc
__global__ void k_binB(const unsigned int* __restrict__ pairs, const int* __restrict__ bbase,
                       int* __restrict__ cnt, float* __restrict__ dis,
                       int* __restrict__ rstart, int* __restrict__ esrc, int N) {
    __shared__ unsigned int h[256];
    __shared__ int sc[256];
    __shared__ unsigned int cur[256];
    int tid = threadIdx.x;
    int b = blockIdx.x;
    int node0 = b << 8;
    h[tid] = 0;
    cur[tid] = 0;
    __syncthreads();
    int r0 = bbase[b], r1 = bbase[b + 1];
    for (int i = r0 + tid; i < r1; i += 256)
        atomicAdd(&h[pairs[i] & 255u], 1u);
    __syncthreads();
    int v = (int)h[tid];
    sc[tid] = v;
    __syncthreads();
    for (int off = 1; off < 256; off <<= 1) {
        int t = (tid >= off) ? sc[tid - off] : 0;
        __syncthreads();
        sc[tid] += t;
        __syncthreads();
    }
    int ex = sc[tid] - v;
    __syncthreads();
    sc[tid] = ex;
    __syncthreads();
    int node = node0 + tid;
    if (node < N) {
        cnt[node] = v;
        dis[node] = rsqrtf((float)(v + 1));
        rstart[node] = r0 + ex;
    }
    for (int i = r0 + tid; i < r1; i += 256) {
        unsigned p = pairs[i];
        unsigned l = p & 255u;
        unsigned off = atomicAdd(&cur[l], 1u);
        esrc[r0 + sc[l] + (int)off] = (int)(p >> 8);
    }
}

// g1[i,:] = bf16( dis[i] * (x[i,:] @ W1) )
__global__ void k_g1(const float* __restrict__ x, const float* __restrict__ W1,
                     const float* __restrict__ dis, unsigned short* __restrict__ g1, int N) {
    __shared__ float w[F0 * F1];
    for (int j = threadIdx.x; j < F0 * F1; j += blockDim.x) w[j] = W1[j];
    __syncthreads();
    int i = blockIdx.x * blockDim.x + threadIdx.x;
    if (i >= N) return;
    float xr[F0];
    const float4* xp = reinterpret_cast<const float4*>(x + (size_t)i * F0);
#pragma unroll
    for (int q = 0; q < F0 / 4; ++q) {
        float4 v = xp[q];
        xr[q * 4 + 0] = v.x; xr[q * 4 + 1] = v.y;
        xr[q * 4 + 2] = v.z; xr[q * 4 + 3] = v.w;
    }
    float d = dis[i];
    float o[F1];
#pragma unroll
    for (int j = 0; j < F1; ++j) o[j] = 0.0f;
#pragma unroll
    for (int k = 0; k < F0; ++k) {
        float xv = xr[k];
#pragma unroll
        for (int j = 0; j < F1; ++j) o[j] = fmaf(xv, w[k * F1 + j], o[j]);
    }
    uint4 pk[4];
    unsigned* pu = reinterpret_cast<unsigned*>(pk);
#pragma unroll
    for (int q = 0; q < 16; ++q) {
        unsigned lo = f2bf(d * o[2 * q]);
        unsigned hi = f2bf(d * o[2 * q + 1]);
        pu[q] = lo | (hi << 16);
    }
    uint4* gp = reinterpret_cast<uint4*>(g1 + (size_t)i * F1);
#pragma unroll
    for (int q = 0; q < 4; ++q) gp[q] = pk[q];
}

// fused layer1 aggregate + bias + relu + W2 GEMM; 8 lanes/node, 4 bf16 each (8B)
__global__ void k_layer1(const unsigned short* __restrict__ g1, const int* __restrict__ cnt,
                         const int* __restrict__ rstart, const int* __restrict__ esrc,
                         const float* __restrict__ dis, const float* __restrict__ b1,
                         const float* __restrict__ W2, float* __restrict__ g2, int N) {
    __shared__ float w[F1 * F2];
    __shared__ float bb[F1];
    for (int j = threadIdx.x; j < F1 * F2; j += blockDim.x) w[j] = W2[j];
    for (int j = threadIdx.x; j < F1; j += blockDim.x) bb[j] = b1[j];
    __syncthreads();
    int t = blockIdx.x * blockDim.x + threadIdx.x;
    int v = t >> 3;
    int q = t & 7;
    if (v >= N) return;
    const uint2* gbase = reinterpret_cast<const uint2*>(g1) + q;   // row = 8 uint2
    uint2 sw = gbase[(size_t)v * 8];                               // self loop g1[v]
    float o0 = bf2f((unsigned short)(sw.x & 0xffff));
    float o1 = bf2f((unsigned short)(sw.x >> 16));
    float o2 = bf2f((unsigned short)(sw.y & 0xffff));
    float o3 = bf2f((unsigned short)(sw.y >> 16));
    int beg = rstart[v];
    int end = beg + cnt[v];
    for (int j = beg; j < end; ++j) {
        int s = esrc[j];
        uint2 a = gbase[(size_t)s * 8];
        o0 += bf2f((unsigned short)(a.x & 0xffff));
        o1 += bf2f((unsigned short)(a.x >> 16));
        o2 += bf2f((unsigned short)(a.y & 0xffff));
        o3 += bf2f((unsigned short)(a.y >> 16));
    }
    float d = dis[v];
    float p0 = 0.0f, p1 = 0.0f;
    float oz[4] = { o0, o1, o2, o3 };
#pragma unroll
    for (int u = 0; u < 4; ++u) {
        int f = q * 4 + u;
        float r = fmaxf(fmaf(d, oz[u], bb[f]), 0.0f);
        p0 = fmaf(r, w[f * F2 + 0], p0);
        p1 = fmaf(r, w[f * F2 + 1], p1);
    }
#pragma unroll
    for (int off = 1; off < 8; off <<= 1) {
        p0 += __shfl_xor(p0, off);
        p1 += __shfl_xor(p1, off);
    }
    if (q == 0) {
        g2[(size_t)v * F2 + 0] = d * p0;
        g2[(size_t)v * F2 + 1] = d * p1;
    }
}

// fused layer2 aggregate + output: 4 lanes per node, strided edges
__global__ void k_out2(const float* __restrict__ g2, const int* __restrict__ cnt,
                       const int* __restrict__ rstart, const int* __restrict__ esrc,
                       const float* __restrict__ dis, const float* __restrict__ b2,
                       float* __restrict__ out, int N) {
    int t = blockIdx.x * blockDim.x + threadIdx.x;
    int v = t >> 2;
    int l = t & 3;
    if (v >= N) return;
    float o0 = 0.0f, o1 = 0.0f;
    int beg = rstart[v];
    int end = beg + cnt[v];
    for (int j = beg + l; j < end; j += 4) {
        int s = esrc[j];
        const float2 a = *reinterpret_cast<const float2*>(g2 + (size_t)s * F2);
        o0 += a.x; o1 += a.y;
    }
#pragma unroll
    for (int off = 1; off < 4; off <<= 1) {
        o0 += __shfl_xor(o0, off);
        o1 += __shfl_xor(o1, off);
    }
    if (l == 0) {
        float d = dis[v];
        const float2 self = *reinterpret_cast<const float2*>(g2 + (size_t)v * F2);
        out[(size_t)v * F2 + 0] = fmaf(d, o0 + self.x, b2[0]);
        out[(size_t)v * F2 + 1] = fmaf(d, o1 + self.y, b2[1]);
    }
}

extern "C" void kernel_launch(void* const* d_in, const int* in_sizes, int n_in,
                              void* d_out, int out_size, void* d_ws, size_t ws_size,
                              hipStream_t stream) {
    const float* x  = (const float*)d_in[0];
    const int* ei   = (const int*)d_in[1];
    const float* W1 = (const float*)d_in[2];
    const float* b1 = (const float*)d_in[3];
    const float* W2 = (const float*)d_in[4];
    const float* b2 = (const float*)d_in[5];
    float* out = (float*)d_out;

    const int N = in_sizes[0] / F0;          // 100000
    const int E = in_sizes[1] / 2;           // 3200000
    const int* src = ei;
    const int* dst = ei + E;
    const int nb = (N + 255) >> 8;           // 391 buckets

    // workspace layout (4-byte units)
    char* wsb = (char*)d_ws;
    unsigned int* btot  = (unsigned int*)wsb;                 // MAXNB*BPAD
    unsigned int* bfill = btot + MAXNB * BPAD;                // MAXNB*BPAD
    int* bbase          = (int*)(bfill + MAXNB * BPAD);       // MAXNB+1
    int* cnt            = bbase + MAXNB + 1;                  // N
    float* dis          = (float*)(cnt + N);                  // N
    int* rstart         = (int*)(dis + N);                    // N
    unsigned int* pairs = (unsigned int*)(rstart + N);        // E
    int* esrc           = (int*)(pairs + E);                  // E
    unsigned short* g1  = (unsigned short*)(esrc + E);        // 32N ushort (16N words)
    float* g2           = (float*)(g1 + (size_t)32 * N);      // 2N
    // total ~ (3N + 2E + 16N + 2N) * 4B  ~= 34 MB

    hipMemsetAsync(btot, 0, (size_t)MAXNB * BPAD * sizeof(int), stream);

    const int B = 256;
    k_bhist<<<nb, B, 0, stream>>>(dst, btot, E, nb, nb);
    k_bscan<<<1, MAXNB, 0, stream>>>(btot, bbase, bfill, nb, E);
    k_binA<<<(E + EPB - 1) / EPB, B, 0, stream>>>(src, dst, bfill, pairs, E, nb);
    k_binB<<<nb, B, 0, stream>>>(pairs, bbase, cnt, dis, rstart, esrc, N);
    k_g1<<<(N + B - 1) / B, B, 0, stream>>>(x, W1, dis, g1, N);
    k_layer1<<<(N * 8 + B - 1) / B, B, 0, stream>>>(g1, cnt, rstart, esrc, dis, b1, W2, g2, N);
    k_out2<<<(N * 4 + B - 1) / B, B, 0, stream>>>(g2, cnt, rstart, esrc, dis, b2, out, N);
}

// Round 6
// 179.431 us; speedup vs baseline: 4.5258x; 1.1210x over previous
//
#include <hip/hip_runtime.h>

// GCN 2-layer via two-level counting-sort CSR + gather-sum (no float atomics).
// norm trick: g = dis * (h @ W); out[v] = dis[v]*(sum_{u->v} g[u] + g[v]) + b
// g1 stored as bf16 -> 64B row = 1 cache line per edge gather.
// layer1/out2 gather loops restructured for 8x / 4x memory-level parallelism.

static constexpr int F0 = 16;
static constexpr int F1 = 32;
static constexpr int F2 = 2;
static constexpr int MAXNB = 512;   // max coarse buckets
static constexpr int BPAD  = 16;    // pad global counters to own 64B line
static constexpr int EPB   = 8192;  // edges per k_binA block

__device__ inline unsigned short f2bf(float f) {
    unsigned u = __float_as_uint(f);
    unsigned r = (u + 0x7fffu + ((u >> 16) & 1u)) >> 16;   // RNE
    return (unsigned short)r;
}
__device__ inline float bf2f(unsigned short b) {
    return __uint_as_float(((unsigned)b) << 16);
}

__global__ void k_bhist(const int* __restrict__ dst, unsigned int* __restrict__ btot,
                        int E, int nb, int nblocks) {
    __shared__ unsigned int h[MAXNB];
    for (int b = threadIdx.x; b < MAXNB; b += blockDim.x) h[b] = 0;
    __syncthreads();
    for (int e = blockIdx.x * blockDim.x + threadIdx.x; e < E; e += nblocks * blockDim.x)
        atomicAdd(&h[((unsigned)dst[e]) >> 8], 1u);
    __syncthreads();
    for (int b = threadIdx.x; b < nb; b += blockDim.x)
        if (h[b]) atomicAdd(&btot[b * BPAD], h[b]);
}

// single block of MAXNB threads: exclusive scan of bucket totals
__global__ void k_bscan(const unsigned int* __restrict__ btot, int* __restrict__ bbase,
                        unsigned int* __restrict__ bfill, int nb, int E) {
    __shared__ int s[MAXNB];
    int tid = threadIdx.x;
    int v = (tid < nb) ? (int)btot[tid * BPAD] : 0;
    s[tid] = v;
    __syncthreads();
    for (int off = 1; off < MAXNB; off <<= 1) {
        int t = (tid >= off) ? s[tid - off] : 0;
        __syncthreads();
        s[tid] += t;
        __syncthreads();
    }
    if (tid < nb) {
        int ex = s[tid] - v;
        bbase[tid] = ex;
        bfill[tid * BPAD] = (unsigned)ex;
    }
    if (tid == 0) bbase[nb] = E;
}

__global__ void k_binA(const int* __restrict__ src, const int* __restrict__ dst,
                       unsigned int* __restrict__ bfill, unsigned int* __restrict__ pairs,
                       int E, int nb) {
    __shared__ unsigned int h[MAXNB];
    __shared__ unsigned int bs[MAXNB];
    __shared__ unsigned int cur[MAXNB];
    for (int b = threadIdx.x; b < MAXNB; b += blockDim.x) { h[b] = 0; cur[b] = 0; }
    __syncthreads();
    int e0 = blockIdx.x * EPB;
    int e1 = min(e0 + EPB, E);
    for (int e = e0 + (int)threadIdx.x; e < e1; e += blockDim.x)
        atomicAdd(&h[((unsigned)dst[e]) >> 8], 1u);
    __syncthreads();
    for (int b = threadIdx.x; b < nb; b += blockDim.x)
        bs[b] = h[b] ? atomicAdd(&bfill[b * BPAD], h[b]) : 0u;
    __syncthreads();
    for (int e = e0 + (int)threadIdx.x; e < e1; e += blockDim.x) {
        unsigned d = (unsigned)dst[e];
        unsigned b = d >> 8;
        unsigned off = atomicAdd(&cur[b], 1u);
        pairs[bs[b] + off] = (((unsigned)src[e]) << 8) | (d & 255u);
    }
}

// one block (256 threads) per bucket: node hist + scan -> cnt/dis/rstart, scatter esrc
__global__ void k_binB(const unsigned int* __restrict__ pairs, const int* __restrict__ bbase,
                       int* __restrict__ cnt, float* __restrict__ dis,
                       int* __restrict__ rstart, int* __restrict__ esrc, int N) {
    __shared__ unsigned int h[256];
    __shared__ int sc[256];
    __shared__ unsigned int cur[256];
    int tid = threadIdx.x;
    int b = blockIdx.x;
    int node0 = b << 8;
    h[tid] = 0;
    cur[tid] = 0;
    __syncthreads();
    int r0 = bbase[b], r1 = bbase[b + 1];
    for (int i = r0 + tid; i < r1; i += 256)
        atomicAdd(&h[pairs[i] & 255u], 1u);
    __syncthreads();
    int v = (int)h[tid];
    sc[tid] = v;
    __syncthreads();
    for (int off = 1; off < 256; off <<= 1) {
        int t = (tid >= off) ? sc[tid - off] : 0;
        __syncthreads();
        sc[tid] += t;
        __syncthreads();
    }
    int ex = sc[tid] - v;
    __syncthreads();
    sc[tid] = ex;
    __syncthreads();
    int node = node0 + tid;
    if (node < N) {
        cnt[node] = v;
        dis[node] = rsqrtf((float)(v + 1));
        rstart[node] = r0 + ex;
    }
    for (int i = r0 + tid; i < r1; i += 256) {
        unsigned p = pairs[i];
        unsigned l = p & 255u;
        unsigned off = atomicAdd(&cur[l], 1u);
        esrc[r0 + sc[l] + (int)off] = (int)(p >> 8);
    }
}

// g1[i,:] = bf16( dis[i] * (x[i,:] @ W1) )
__global__ void k_g1(const float* __restrict__ x, const float* __restrict__ W1,
                     const float* __restrict__ dis, unsigned short* __restrict__ g1, int N) {
    __shared__ float w[F0 * F1];
    for (int j = threadIdx.x; j < F0 * F1; j += blockDim.x) w[j] = W1[j];
    __syncthreads();
    int i = blockIdx.x * blockDim.x + threadIdx.x;
    if (i >= N) return;
    float xr[F0];
    const float4* xp = reinterpret_cast<const float4*>(x + (size_t)i * F0);
#pragma unroll
    for (int q = 0; q < F0 / 4; ++q) {
        float4 v = xp[q];
        xr[q * 4 + 0] = v.x; xr[q * 4 + 1] = v.y;
        xr[q * 4 + 2] = v.z; xr[q * 4 + 3] = v.w;
    }
    float d = dis[i];
    float o[F1];
#pragma unroll
    for (int j = 0; j < F1; ++j) o[j] = 0.0f;
#pragma unroll
    for (int k = 0; k < F0; ++k) {
        float xv = xr[k];
#pragma unroll
        for (int j = 0; j < F1; ++j) o[j] = fmaf(xv, w[k * F1 + j], o[j]);
    }
    uint4 pk[4];
    unsigned* pu = reinterpret_cast<unsigned*>(pk);
#pragma unroll
    for (int q = 0; q < 16; ++q) {
        unsigned lo = f2bf(d * o[2 * q]);
        unsigned hi = f2bf(d * o[2 * q + 1]);
        pu[q] = lo | (hi << 16);
    }
    uint4* gp = reinterpret_cast<uint4*>(g1 + (size_t)i * F1);
#pragma unroll
    for (int q = 0; q < 4; ++q) gp[q] = pk[q];
}

// fused layer1 aggregate + bias + relu + W2 GEMM; 8 lanes/node, 4 bf16 each (8B).
// Edge loop in chunks of 8: each lane loads one distinct esrc entry (32B
// coalesced per group), then 8 shfl-broadcast gathers issued back-to-back.
__global__ void k_layer1(const unsigned short* __restrict__ g1, const int* __restrict__ cnt,
                         const int* __restrict__ rstart, const int* __restrict__ esrc,
                         const float* __restrict__ dis, const float* __restrict__ b1,
                         const float* __restrict__ W2, float* __restrict__ g2, int N) {
    __shared__ float w[F1 * F2];
    __shared__ float bb[F1];
    for (int j = threadIdx.x; j < F1 * F2; j += blockDim.x) w[j] = W2[j];
    for (int j = threadIdx.x; j < F1; j += blockDim.x) bb[j] = b1[j];
    __syncthreads();
    int t = blockIdx.x * blockDim.x + threadIdx.x;
    int v = t >> 3;
    int q = t & 7;
    if (v >= N) return;
    const uint2* gbase = reinterpret_cast<const uint2*>(g1) + q;   // row = 8 uint2
    uint2 sw = gbase[(size_t)v * 8];                               // self loop g1[v]
    float o0 = bf2f((unsigned short)(sw.x & 0xffff));
    float o1 = bf2f((unsigned short)(sw.x >> 16));
    float o2 = bf2f((unsigned short)(sw.y & 0xffff));
    float o3 = bf2f((unsigned short)(sw.y >> 16));
    int beg = rstart[v];
    int n = cnt[v];
    int n8 = n & ~7;
    for (int j = 0; j < n8; j += 8) {
        int idx = esrc[beg + j + q];       // 8 distinct edges across the group
#pragma unroll
        for (int u = 0; u < 8; ++u) {
            int s = __shfl(idx, u, 8);
            uint2 a = gbase[(size_t)s * 8];
            o0 += bf2f((unsigned short)(a.x & 0xffff));
            o1 += bf2f((unsigned short)(a.x >> 16));
            o2 += bf2f((unsigned short)(a.y & 0xffff));
            o3 += bf2f((unsigned short)(a.y >> 16));
        }
    }
    for (int j = n8; j < n; ++j) {         // tail: uniform load
        int s = esrc[beg + j];
        uint2 a = gbase[(size_t)s * 8];
        o0 += bf2f((unsigned short)(a.x & 0xffff));
        o1 += bf2f((unsigned short)(a.x >> 16));
        o2 += bf2f((unsigned short)(a.y & 0xffff));
        o3 += bf2f((unsigned short)(a.y >> 16));
    }
    float d = dis[v];
    float p0 = 0.0f, p1 = 0.0f;
    float oz[4] = { o0, o1, o2, o3 };
#pragma unroll
    for (int u = 0; u < 4; ++u) {
        int f = q * 4 + u;
        float r = fmaxf(fmaf(d, oz[u], bb[f]), 0.0f);
        p0 = fmaf(r, w[f * F2 + 0], p0);
        p1 = fmaf(r, w[f * F2 + 1], p1);
    }
#pragma unroll
    for (int off = 1; off < 8; off <<= 1) {
        p0 += __shfl_xor(p0, off);
        p1 += __shfl_xor(p1, off);
    }
    if (q == 0) {
        g2[(size_t)v * F2 + 0] = d * p0;
        g2[(size_t)v * F2 + 1] = d * p1;
    }
}

// fused layer2 aggregate + output: 4 lanes per node, strided edges, 4x unroll
__global__ void k_out2(const float* __restrict__ g2, const int* __restrict__ cnt,
                       const int* __restrict__ rstart, const int* __restrict__ esrc,
                       const float* __restrict__ dis, const float* __restrict__ b2,
                       float* __restrict__ out, int N) {
    int t = blockIdx.x * blockDim.x + threadIdx.x;
    int v = t >> 2;
    int l = t & 3;
    if (v >= N) return;
    float o0 = 0.0f, o1 = 0.0f;
    int beg = rstart[v];
    int end = beg + cnt[v];
    int j = beg + l;
    for (; j + 12 < end; j += 16) {        // 4 independent gathers in flight
        int s0 = esrc[j];
        int s1 = esrc[j + 4];
        int s2 = esrc[j + 8];
        int s3 = esrc[j + 12];
        float2 a0 = *reinterpret_cast<const float2*>(g2 + (size_t)s0 * F2);
        float2 a1 = *reinterpret_cast<const float2*>(g2 + (size_t)s1 * F2);
        float2 a2 = *reinterpret_cast<const float2*>(g2 + (size_t)s2 * F2);
        float2 a3 = *reinterpret_cast<const float2*>(g2 + (size_t)s3 * F2);
        o0 += a0.x + a1.x + a2.x + a3.x;
        o1 += a0.y + a1.y + a2.y + a3.y;
    }
    for (; j < end; j += 4) {
        int s = esrc[j];
        const float2 a = *reinterpret_cast<const float2*>(g2 + (size_t)s * F2);
        o0 += a.x; o1 += a.y;
    }
#pragma unroll
    for (int off = 1; off < 4; off <<= 1) {
        o0 += __shfl_xor(o0, off);
        o1 += __shfl_xor(o1, off);
    }
    if (l == 0) {
        float d = dis[v];
        const float2 self = *reinterpret_cast<const float2*>(g2 + (size_t)v * F2);
        out[(size_t)v * F2 + 0] = fmaf(d, o0 + self.x, b2[0]);
        out[(size_t)v * F2 + 1] = fmaf(d, o1 + self.y, b2[1]);
    }
}

extern "C" void kernel_launch(void* const* d_in, const int* in_sizes, int n_in,
                              void* d_out, int out_size, void* d_ws, size_t ws_size,
                              hipStream_t stream) {
    const float* x  = (const float*)d_in[0];
    const int* ei   = (const int*)d_in[1];
    const float* W1 = (const float*)d_in[2];
    const float* b1 = (const float*)d_in[3];
    const float* W2 = (const float*)d_in[4];
    const float* b2 = (const float*)d_in[5];
    float* out = (float*)d_out;

    const int N = in_sizes[0] / F0;          // 100000
    const int E = in_sizes[1] / 2;           // 3200000
    const int* src = ei;
    const int* dst = ei + E;
    const int nb = (N + 255) >> 8;           // 391 buckets

    // workspace layout (4-byte units)
    char* wsb = (char*)d_ws;
    unsigned int* btot  = (unsigned int*)wsb;                 // MAXNB*BPAD
    unsigned int* bfill = btot + MAXNB * BPAD;                // MAXNB*BPAD
    int* bbase          = (int*)(bfill + MAXNB * BPAD);       // MAXNB+1
    int* cnt            = bbase + MAXNB + 1;                  // N
    float* dis          = (float*)(cnt + N);                  // N
    int* rstart         = (int*)(dis + N);                    // N
    unsigned int* pairs = (unsigned int*)(rstart + N);        // E
    int* esrc           = (int*)(pairs + E);                  // E
    unsigned short* g1  = (unsigned short*)(esrc + E);        // 32N ushort (16N words)
    float* g2           = (float*)(g1 + (size_t)32 * N);      // 2N
    // total ~ (3N + 2E + 16N + 2N) * 4B  ~= 34 MB

    hipMemsetAsync(btot, 0, (size_t)MAXNB * BPAD * sizeof(int), stream);

    const int B = 256;
    k_bhist<<<nb, B, 0, stream>>>(dst, btot, E, nb, nb);
    k_bscan<<<1, MAXNB, 0, stream>>>(btot, bbase, bfill, nb, E);
    k_binA<<<(E + EPB - 1) / EPB, B, 0, stream>>>(src, dst, bfill, pairs, E, nb);
    k_binB<<<nb, B, 0, stream>>>(pairs, bbase, cnt, dis, rstart, esrc, N);
    k_g1<<<(N + B - 1) / B, B, 0, stream>>>(x, W1, dis, g1, N);
    k_layer1<<<(N * 8 + B - 1) / B, B, 0, stream>>>(g1, cnt, rstart, esrc, dis, b1, W2, g2, N);
    k_out2<<<(N * 4 + B - 1) / B, B, 0, stream>>>(g2, cnt, rstart, esrc, dis, b2, out, N);
}

// Round 7
// 179.338 us; speedup vs baseline: 4.5281x; 1.0005x over previous
//
#include <hip/hip_runtime.h>

// GCN 2-layer via two-level counting-sort CSR + gather-sum (no float atomics).
// norm trick: g = dis * (h @ W); out[v] = dis[v]*(sum_{u->v} g[u] + g[v]) + b
// g1 stored as bf16 -> 64B row = 1 cache line per edge gather.
// binA reservations padded to 16 slots (64B) so each block owns its cache
// lines exclusively (kills cross-XCD write amplification); sentinel-filled.

static constexpr int F0 = 16;
static constexpr int F1 = 32;
static constexpr int F2 = 2;
static constexpr int MAXNB = 512;   // max coarse buckets
static constexpr int BPAD  = 16;    // pad global counters to own 64B line
static constexpr int EPB   = 8192;  // edges per binA/bhist block (same chunking!)
static constexpr unsigned SENT = 0xFFFFFFFFu;

__device__ inline unsigned roundup16(unsigned h) { return (h + 15u) & ~15u; }

__device__ inline unsigned short f2bf(float f) {
    unsigned u = __float_as_uint(f);
    unsigned r = (u + 0x7fffu + ((u >> 16) & 1u)) >> 16;   // RNE
    return (unsigned short)r;
}
__device__ inline float bf2f(unsigned short b) {
    return __uint_as_float(((unsigned)b) << 16);
}

// per-chunk bucket histogram; accumulates PADDED per-block totals
__global__ void k_bhist(const int* __restrict__ dst, unsigned int* __restrict__ btot,
                        int E, int nb) {
    __shared__ unsigned int h[MAXNB];
    for (int b = threadIdx.x; b < MAXNB; b += blockDim.x) h[b] = 0;
    __syncthreads();
    int e0 = blockIdx.x * EPB;
    int e1 = min(e0 + EPB, E);
    for (int e = e0 + (int)threadIdx.x; e < e1; e += blockDim.x)
        atomicAdd(&h[((unsigned)dst[e]) >> 8], 1u);
    __syncthreads();
    for (int b = threadIdx.x; b < nb; b += blockDim.x)
        if (h[b]) atomicAdd(&btot[b * BPAD], roundup16(h[b]));
}

// single block of MAXNB threads: exclusive scan of padded bucket totals
__global__ void k_bscan(const unsigned int* __restrict__ btot, int* __restrict__ bbase,
                        unsigned int* __restrict__ bfill, int nb) {
    __shared__ int s[MAXNB];
    int tid = threadIdx.x;
    int v = (tid < nb) ? (int)btot[tid * BPAD] : 0;
    s[tid] = v;
    __syncthreads();
    for (int off = 1; off < MAXNB; off <<= 1) {
        int t = (tid >= off) ? s[tid - off] : 0;
        __syncthreads();
        s[tid] += t;
        __syncthreads();
    }
    if (tid < nb) {
        int ex = s[tid] - v;
        bbase[tid] = ex;
        bfill[tid * BPAD] = (unsigned)ex;
    }
    if (tid == nb - 1) bbase[nb] = s[tid];   // padded grand total
}

__global__ void k_binA(const int* __restrict__ src, const int* __restrict__ dst,
                       unsigned int* __restrict__ bfill, unsigned int* __restrict__ pairs,
                       int E, int nb) {
    __shared__ unsigned int h[MAXNB];
    __shared__ unsigned int bs[MAXNB];
    __shared__ unsigned int cur[MAXNB];
    for (int b = threadIdx.x; b < MAXNB; b += blockDim.x) { h[b] = 0; cur[b] = 0; }
    __syncthreads();
    int e0 = blockIdx.x * EPB;
    int e1 = min(e0 + EPB, E);
    for (int e = e0 + (int)threadIdx.x; e < e1; e += blockDim.x)
        atomicAdd(&h[((unsigned)dst[e]) >> 8], 1u);
    __syncthreads();
    for (int b = threadIdx.x; b < nb; b += blockDim.x)
        bs[b] = h[b] ? atomicAdd(&bfill[b * BPAD], roundup16(h[b])) : 0u;  // 64B-aligned
    __syncthreads();
    for (int e = e0 + (int)threadIdx.x; e < e1; e += blockDim.x) {
        unsigned d = (unsigned)dst[e];
        unsigned b = d >> 8;
        unsigned off = atomicAdd(&cur[b], 1u);
        pairs[bs[b] + off] = (((unsigned)src[e]) << 8) | (d & 255u);
    }
    __syncthreads();
    // sentinel-fill the pad slots (lines are exclusively ours -> clean writes)
    for (int b = threadIdx.x; b < nb; b += blockDim.x) {
        unsigned hb = h[b];
        if (!hb) continue;
        unsigned s0 = bs[b] + hb;
        unsigned s1 = bs[b] + roundup16(hb);
        for (unsigned k = s0; k < s1; ++k) pairs[k] = SENT;
    }
}

// one block (256 threads) per bucket: node hist + scan -> cnt/dis/rstart,
// compact scatter of src into esrc via global cursor
__global__ void k_binB(const unsigned int* __restrict__ pairs, const int* __restrict__ bbase,
                       unsigned int* __restrict__ ecur,
                       int* __restrict__ cnt, float* __restrict__ dis,
                       int* __restrict__ rstart, int* __restrict__ esrc, int N) {
    __shared__ unsigned int h[256];
    __shared__ int sc[256];
    __shared__ unsigned int cur[256];
    __shared__ int base;
    int tid = threadIdx.x;
    int b = blockIdx.x;
    int node0 = b << 8;
    h[tid] = 0;
    cur[tid] = 0;
    __syncthreads();
    int r0 = bbase[b], r1 = bbase[b + 1];
    for (int i = r0 + tid; i < r1; i += 256) {
        unsigned p = pairs[i];
        if (p != SENT) atomicAdd(&h[p & 255u], 1u);
    }
    __syncthreads();
    int v = (int)h[tid];
    sc[tid] = v;
    __syncthreads();
    for (int off = 1; off < 256; off <<= 1) {
        int t = (tid >= off) ? sc[tid - off] : 0;
        __syncthreads();
        sc[tid] += t;
        __syncthreads();
    }
    int ex = sc[tid] - v;
    __syncthreads();
    sc[tid] = ex;
    if (tid == 255) base = (int)atomicAdd(ecur, (unsigned)(ex + v));
    __syncthreads();
    int node = node0 + tid;
    if (node < N) {
        cnt[node] = v;
        dis[node] = rsqrtf((float)(v + 1));
        rstart[node] = base + ex;
    }
    for (int i = r0 + tid; i < r1; i += 256) {
        unsigned p = pairs[i];
        if (p == SENT) continue;
        unsigned l = p & 255u;
        unsigned off = atomicAdd(&cur[l], 1u);
        esrc[base + sc[l] + (int)off] = (int)(p >> 8);
    }
}

// g1[i,:] = bf16( dis[i] * (x[i,:] @ W1) )
__global__ void k_g1(const float* __restrict__ x, const float* __restrict__ W1,
                     const float* __restrict__ dis, unsigned short* __restrict__ g1, int N) {
    __shared__ float w[F0 * F1];
    for (int j = threadIdx.x; j < F0 * F1; j += blockDim.x) w[j] = W1[j];
    __syncthreads();
    int i = blockIdx.x * blockDim.x + threadIdx.x;
    if (i >= N) return;
    float xr[F0];
    const float4* xp = reinterpret_cast<const float4*>(x + (size_t)i * F0);
#pragma unroll
    for (int q = 0; q < F0 / 4; ++q) {
        float4 v = xp[q];
        xr[q * 4 + 0] = v.x; xr[q * 4 + 1] = v.y;
        xr[q * 4 + 2] = v.z; xr[q * 4 + 3] = v.w;
    }
    float d = dis[i];
    float o[F1];
#pragma unroll
    for (int j = 0; j < F1; ++j) o[j] = 0.0f;
#pragma unroll
    for (int k = 0; k < F0; ++k) {
        float xv = xr[k];
#pragma unroll
        for (int j = 0; j < F1; ++j) o[j] = fmaf(xv, w[k * F1 + j], o[j]);
    }
    uint4 pk[4];
    unsigned* pu = reinterpret_cast<unsigned*>(pk);
#pragma unroll
    for (int q = 0; q < 16; ++q) {
        unsigned lo = f2bf(d * o[2 * q]);
        unsigned hi = f2bf(d * o[2 * q + 1]);
        pu[q] = lo | (hi << 16);
    }
    uint4* gp = reinterpret_cast<uint4*>(g1 + (size_t)i * F1);
#pragma unroll
    for (int q = 0; q < 4; ++q) gp[q] = pk[q];
}

// fused layer1 aggregate + bias + relu + W2 GEMM; 8 lanes/node, 4 bf16 each (8B).
__global__ void k_layer1(const unsigned short* __restrict__ g1, const int* __restrict__ cnt,
                         const int* __restrict__ rstart, const int* __restrict__ esrc,
                         const float* __restrict__ dis, const float* __restrict__ b1,
                         const float* __restrict__ W2, float* __restrict__ g2, int N) {
    __shared__ float w[F1 * F2];
    __shared__ float bb[F1];
    for (int j = threadIdx.x; j < F1 * F2; j += blockDim.x) w[j] = W2[j];
    for (int j = threadIdx.x; j < F1; j += blockDim.x) bb[j] = b1[j];
    __syncthreads();
    int t = blockIdx.x * blockDim.x + threadIdx.x;
    int v = t >> 3;
    int q = t & 7;
    if (v >= N) return;
    const uint2* gbase = reinterpret_cast<const uint2*>(g1) + q;   // row = 8 uint2
    uint2 sw = gbase[(size_t)v * 8];                               // self loop g1[v]
    float o0 = bf2f((unsigned short)(sw.x & 0xffff));
    float o1 = bf2f((unsigned short)(sw.x >> 16));
    float o2 = bf2f((unsigned short)(sw.y & 0xffff));
    float o3 = bf2f((unsigned short)(sw.y >> 16));
    int beg = rstart[v];
    int n = cnt[v];
    int n8 = n & ~7;
    for (int j = 0; j < n8; j += 8) {
        int idx = esrc[beg + j + q];       // 8 distinct edges across the group
#pragma unroll
        for (int u = 0; u < 8; ++u) {
            int s = __shfl(idx, u, 8);
            uint2 a = gbase[(size_t)s * 8];
            o0 += bf2f((unsigned short)(a.x & 0xffff));
            o1 += bf2f((unsigned short)(a.x >> 16));
            o2 += bf2f((unsigned short)(a.y & 0xffff));
            o3 += bf2f((unsigned short)(a.y >> 16));
        }
    }
    for (int j = n8; j < n; ++j) {         // tail: uniform load
        int s = esrc[beg + j];
        uint2 a = gbase[(size_t)s * 8];
        o0 += bf2f((unsigned short)(a.x & 0xffff));
        o1 += bf2f((unsigned short)(a.x >> 16));
        o2 += bf2f((unsigned short)(a.y & 0xffff));
        o3 += bf2f((unsigned short)(a.y >> 16));
    }
    float d = dis[v];
    float p0 = 0.0f, p1 = 0.0f;
    float oz[4] = { o0, o1, o2, o3 };
#pragma unroll
    for (int u = 0; u < 4; ++u) {
        int f = q * 4 + u;
        float r = fmaxf(fmaf(d, oz[u], bb[f]), 0.0f);
        p0 = fmaf(r, w[f * F2 + 0], p0);
        p1 = fmaf(r, w[f * F2 + 1], p1);
    }
#pragma unroll
    for (int off = 1; off < 8; off <<= 1) {
        p0 += __shfl_xor(p0, off);
        p1 += __shfl_xor(p1, off);
    }
    if (q == 0) {
        g2[(size_t)v * F2 + 0] = d * p0;
        g2[(size_t)v * F2 + 1] = d * p1;
    }
}

// fused layer2 aggregate + output: 4 lanes per node, strided edges, 4x unroll
__global__ void k_out2(const float* __restrict__ g2, const int* __restrict__ cnt,
                       const int* __restrict__ rstart, const int* __restrict__ esrc,
                       const float* __restrict__ dis, const float* __restrict__ b2,
                       float* __restrict__ out, int N) {
    int t = blockIdx.x * blockDim.x + threadIdx.x;
    int v = t >> 2;
    int l = t & 3;
    if (v >= N) return;
    float o0 = 0.0f, o1 = 0.0f;
    int beg = rstart[v];
    int end = beg + cnt[v];
    int j = beg + l;
    for (; j + 12 < end; j += 16) {        // 4 independent gathers in flight
        int s0 = esrc[j];
        int s1 = esrc[j + 4];
        int s2 = esrc[j + 8];
        int s3 = esrc[j + 12];
        float2 a0 = *reinterpret_cast<const float2*>(g2 + (size_t)s0 * F2);
        float2 a1 = *reinterpret_cast<const float2*>(g2 + (size_t)s1 * F2);
        float2 a2 = *reinterpret_cast<const float2*>(g2 + (size_t)s2 * F2);
        float2 a3 = *reinterpret_cast<const float2*>(g2 + (size_t)s3 * F2);
        o0 += a0.x + a1.x + a2.x + a3.x;
        o1 += a0.y + a1.y + a2.y + a3.y;
    }
    for (; j < end; j += 4) {
        int s = esrc[j];
        const float2 a = *reinterpret_cast<const float2*>(g2 + (size_t)s * F2);
        o0 += a.x; o1 += a.y;
    }
#pragma unroll
    for (int off = 1; off < 4; off <<= 1) {
        o0 += __shfl_xor(o0, off);
        o1 += __shfl_xor(o1, off);
    }
    if (l == 0) {
        float d = dis[v];
        const float2 self = *reinterpret_cast<const float2*>(g2 + (size_t)v * F2);
        out[(size_t)v * F2 + 0] = fmaf(d, o0 + self.x, b2[0]);
        out[(size_t)v * F2 + 1] = fmaf(d, o1 + self.y, b2[1]);
    }
}

extern "C" void kernel_launch(void* const* d_in, const int* in_sizes, int n_in,
                              void* d_out, int out_size, void* d_ws, size_t ws_size,
                              hipStream_t stream) {
    const float* x  = (const float*)d_in[0];
    const int* ei   = (const int*)d_in[1];
    const float* W1 = (const float*)d_in[2];
    const float* b1 = (const float*)d_in[3];
    const float* W2 = (const float*)d_in[4];
    const float* b2 = (const float*)d_in[5];
    float* out = (float*)d_out;

    const int N = in_sizes[0] / F0;          // 100000
    const int E = in_sizes[1] / 2;           // 3200000
    const int* src = ei;
    const int* dst = ei + E;
    const int nb = (N + 255) >> 8;           // 391 buckets
    const int nchunk = (E + EPB - 1) / EPB;  // 391 chunks
    const size_t pairs_cap = (size_t)E + (size_t)nchunk * nb * 16;  // padded capacity

    // workspace layout (4-byte units)
    char* wsb = (char*)d_ws;
    unsigned int* btot  = (unsigned int*)wsb;                 // MAXNB*BPAD
    unsigned int* bfill = btot + MAXNB * BPAD;                // MAXNB*BPAD
    unsigned int* ecur  = bfill + MAXNB * BPAD;               // 16 (line pad)
    int* bbase          = (int*)(ecur + 16);                  // MAXNB+1
    int* cnt            = bbase + MAXNB + 1;                  // N
    float* dis          = (float*)(cnt + N);                  // N
    int* rstart         = (int*)(dis + N);                    // N
    unsigned int* pairs = (unsigned int*)(rstart + N);        // pairs_cap
    int* esrc           = (int*)(pairs + pairs_cap);          // E
    unsigned short* g1  = (unsigned short*)(esrc + E);        // 32N ushort
    float* g2           = (float*)(g1 + (size_t)32 * N);      // 2N
    // total ~ (2E + 2.5M + 21N) * 4B ~= 45 MB

    hipMemsetAsync(btot, 0, ((size_t)2 * MAXNB * BPAD + 16) * sizeof(int), stream);

    const int B = 256;
    k_bhist<<<nchunk, 512, 0, stream>>>(dst, btot, E, nb);
    k_bscan<<<1, MAXNB, 0, stream>>>(btot, bbase, bfill, nb);
    k_binA<<<nchunk, 512, 0, stream>>>(src, dst, bfill, pairs, E, nb);
    k_binB<<<nb, B, 0, stream>>>(pairs, bbase, ecur, cnt, dis, rstart, esrc, N);
    k_g1<<<(N + B - 1) / B, B, 0, stream>>>(x, W1, dis, g1, N);
    k_layer1<<<(N * 8 + B - 1) / B, B, 0, stream>>>(g1, cnt, rstart, esrc, dis, b1, W2, g2, N);
    k_out2<<<(N * 4 + B - 1) / B, B, 0, stream>>>(g2, cnt, rstart, esrc, dis, b2, out, N);
}

// Round 8
// 164.480 us; speedup vs baseline: 4.9371x; 1.0903x over previous
//
#include <hip/hip_runtime.h>

// GCN 2-layer via two-level counting-sort CSR + gather-sum (no float atomics).
// norm trick: g = dis * (h @ W); out[v] = dis[v]*(sum_{u->v} g[u] + g[v]) + b
// g1 stored as bf16 -> 64B row = 1 cache line per edge gather.
// binA: per-chunk LDS counting sort, then per-bucket WAVE burst copy (uint4,
// 64B-aligned exclusive regions) -> coalesced full-line writes, no RFO thrash.

static constexpr int F0 = 16;
static constexpr int F1 = 32;
static constexpr int F2 = 2;
static constexpr int BSH   = 9;     // bucket = dst>>9 (512 nodes/bucket)
static constexpr int BMSK  = 511;
static constexpr int MAXNB = 256;   // max coarse buckets (N<=131072)
static constexpr int BPAD  = 16;    // pad global counters to own 64B line
static constexpr int EPB   = 8192;  // edges per binA/bhist chunk (same!)
static constexpr int SORTCAP = EPB + MAXNB * 16;   // 12288 slots
static constexpr unsigned SENT = 0xFFFFFFFFu;

__device__ inline unsigned roundup16(unsigned h) { return (h + 15u) & ~15u; }

__device__ inline unsigned short f2bf(float f) {
    unsigned u = __float_as_uint(f);
    unsigned r = (u + 0x7fffu + ((u >> 16) & 1u)) >> 16;   // RNE
    return (unsigned short)r;
}
__device__ inline float bf2f(unsigned short b) {
    return __uint_as_float(((unsigned)b) << 16);
}

// per-chunk bucket histogram; accumulates PADDED per-chunk totals
__global__ __launch_bounds__(512) void k_bhist(const int* __restrict__ dst,
                                               unsigned int* __restrict__ btot,
                                               int E, int nb) {
    __shared__ unsigned int h[MAXNB];
    for (int b = threadIdx.x; b < MAXNB; b += blockDim.x) h[b] = 0;
    __syncthreads();
    int e0 = blockIdx.x * EPB;
    int e1 = min(e0 + EPB, E);
    for (int e = e0 + (int)threadIdx.x; e < e1; e += blockDim.x)
        atomicAdd(&h[((unsigned)dst[e]) >> BSH], 1u);
    __syncthreads();
    for (int b = threadIdx.x; b < nb; b += blockDim.x)
        if (h[b]) atomicAdd(&btot[b * BPAD], roundup16(h[b]));
}

// single block of MAXNB threads: exclusive scan of padded bucket totals
__global__ void k_bscan(const unsigned int* __restrict__ btot, int* __restrict__ bbase,
                        unsigned int* __restrict__ bfill, int nb) {
    __shared__ int s[MAXNB];
    int tid = threadIdx.x;
    int v = (tid < nb) ? (int)btot[tid * BPAD] : 0;
    s[tid] = v;
    __syncthreads();
    for (int off = 1; off < MAXNB; off <<= 1) {
        int t = (tid >= off) ? s[tid - off] : 0;
        __syncthreads();
        s[tid] += t;
        __syncthreads();
    }
    if (tid < nb) {
        int ex = s[tid] - v;
        bbase[tid] = ex;
        bfill[tid * BPAD] = (unsigned)ex;
    }
    if (tid == nb - 1) bbase[nb] = s[tid];   // padded grand total
}

// LDS counting sort of the chunk, then per-bucket wave burst copy to global
__global__ __launch_bounds__(512) void k_binA(const int* __restrict__ src,
                                              const int* __restrict__ dst,
                                              unsigned int* __restrict__ bfill,
                                              unsigned int* __restrict__ pairs,
                                              int E, int nb) {
    __shared__ unsigned int h[MAXNB];
    __shared__ unsigned int lbase[MAXNB];
    __shared__ unsigned int bs[MAXNB];
    __shared__ unsigned int cur[MAXNB];
    __shared__ __attribute__((aligned(16))) unsigned int sorted[SORTCAP];
    int tid = threadIdx.x;
    for (int b = tid; b < MAXNB; b += 512) { h[b] = 0; cur[b] = 0; }
    for (int i = tid; i < SORTCAP; i += 512) sorted[i] = SENT;
    __syncthreads();
    int e0 = blockIdx.x * EPB;
    int e1 = min(e0 + EPB, E);
    for (int e = e0 + tid; e < e1; e += 512)
        atomicAdd(&h[((unsigned)dst[e]) >> BSH], 1u);
    __syncthreads();
    // exclusive scan of roundup16(h[]) over MAXNB entries (first 256 threads)
    if (tid < MAXNB) lbase[tid] = roundup16(h[tid]);
    __syncthreads();
    for (int off = 1; off < MAXNB; off <<= 1) {
        unsigned t = (tid >= off && tid < MAXNB) ? lbase[tid - off] : 0u;
        __syncthreads();
        if (tid < MAXNB) lbase[tid] += t;
        __syncthreads();
    }
    if (tid < MAXNB) lbase[tid] -= roundup16(h[tid]);   // exclusive
    // reserve 64B-aligned global regions
    if (tid < nb && h[tid]) bs[tid] = atomicAdd(&bfill[tid * BPAD], roundup16(h[tid]));
    __syncthreads();
    // scatter into LDS (cheap: LDS atomics + LDS writes)
    for (int e = e0 + tid; e < e1; e += 512) {
        unsigned d = (unsigned)dst[e];
        unsigned b = d >> BSH;
        unsigned pos = lbase[b] + atomicAdd(&cur[b], 1u);
        sorted[pos] = (((unsigned)src[e]) << BSH) | (d & BMSK);
    }
    __syncthreads();
    // burst copy: one wave per bucket, uint4 contiguous stores
    int wid = tid >> 6;
    int lane = tid & 63;
    for (int b = wid; b < nb; b += 8) {
        unsigned np = roundup16(h[b]) >> 2;   // uint4 count
        if (!np) continue;
        const uint4* sp = reinterpret_cast<const uint4*>(&sorted[lbase[b]]);
        uint4* gp = reinterpret_cast<uint4*>(&pairs[bs[b]]);
        for (unsigned k = lane; k < np; k += 64) gp[k] = sp[k];
    }
}

// one block (512 threads) per bucket: node hist + scan -> cnt/dis/rstart,
// compact scatter of src into esrc via global cursor
__global__ __launch_bounds__(512) void k_binB(const unsigned int* __restrict__ pairs,
                                              const int* __restrict__ bbase,
                                              unsigned int* __restrict__ ecur,
                                              int* __restrict__ cnt, float* __restrict__ dis,
                                              int* __restrict__ rstart, int* __restrict__ esrc,
                                              int N) {
    __shared__ unsigned int h[512];
    __shared__ int sc[512];
    __shared__ unsigned int cur[512];
    __shared__ int base;
    int tid = threadIdx.x;
    int b = blockIdx.x;
    int node0 = b << BSH;
    h[tid] = 0;
    cur[tid] = 0;
    __syncthreads();
    int r0 = bbase[b], r1 = bbase[b + 1];
    for (int i = r0 + tid; i < r1; i += 512) {
        unsigned p = pairs[i];
        if (p != SENT) atomicAdd(&h[p & BMSK], 1u);
    }
    __syncthreads();
    int v = (int)h[tid];
    sc[tid] = v;
    __syncthreads();
    for (int off = 1; off < 512; off <<= 1) {
        int t = (tid >= off) ? sc[tid - off] : 0;
        __syncthreads();
        sc[tid] += t;
        __syncthreads();
    }
    int ex = sc[tid] - v;
    __syncthreads();
    sc[tid] = ex;
    if (tid == 511) base = (int)atomicAdd(ecur, (unsigned)(ex + v));
    __syncthreads();
    int node = node0 + tid;
    if (node < N) {
        cnt[node] = v;
        dis[node] = rsqrtf((float)(v + 1));
        rstart[node] = base + ex;
    }
    for (int i = r0 + tid; i < r1; i += 512) {
        unsigned p = pairs[i];
        if (p == SENT) continue;
        unsigned l = p & BMSK;
        unsigned off = atomicAdd(&cur[l], 1u);
        esrc[base + sc[l] + (int)off] = (int)(p >> BSH);
    }
}

// g1[i,:] = bf16( dis[i] * (x[i,:] @ W1) )
__global__ void k_g1(const float* __restrict__ x, const float* __restrict__ W1,
                     const float* __restrict__ dis, unsigned short* __restrict__ g1, int N) {
    __shared__ float w[F0 * F1];
    for (int j = threadIdx.x; j < F0 * F1; j += blockDim.x) w[j] = W1[j];
    __syncthreads();
    int i = blockIdx.x * blockDim.x + threadIdx.x;
    if (i >= N) return;
    float xr[F0];
    const float4* xp = reinterpret_cast<const float4*>(x + (size_t)i * F0);
#pragma unroll
    for (int q = 0; q < F0 / 4; ++q) {
        float4 v = xp[q];
        xr[q * 4 + 0] = v.x; xr[q * 4 + 1] = v.y;
        xr[q * 4 + 2] = v.z; xr[q * 4 + 3] = v.w;
    }
    float d = dis[i];
    float o[F1];
#pragma unroll
    for (int j = 0; j < F1; ++j) o[j] = 0.0f;
#pragma unroll
    for (int k = 0; k < F0; ++k) {
        float xv = xr[k];
#pragma unroll
        for (int j = 0; j < F1; ++j) o[j] = fmaf(xv, w[k * F1 + j], o[j]);
    }
    uint4 pk[4];
    unsigned* pu = reinterpret_cast<unsigned*>(pk);
#pragma unroll
    for (int q = 0; q < 16; ++q) {
        unsigned lo = f2bf(d * o[2 * q]);
        unsigned hi = f2bf(d * o[2 * q + 1]);
        pu[q] = lo | (hi << 16);
    }
    uint4* gp = reinterpret_cast<uint4*>(g1 + (size_t)i * F1);
#pragma unroll
    for (int q = 0; q < 4; ++q) gp[q] = pk[q];
}

// fused layer1 aggregate + bias + relu + W2 GEMM; 8 lanes/node, 4 bf16 each (8B).
__global__ void k_layer1(const unsigned short* __restrict__ g1, const int* __restrict__ cnt,
                         const int* __restrict__ rstart, const int* __restrict__ esrc,
                         const float* __restrict__ dis, const float* __restrict__ b1,
                         const float* __restrict__ W2, float* __restrict__ g2, int N) {
    __shared__ float w[F1 * F2];
    __shared__ float bb[F1];
    for (int j = threadIdx.x; j < F1 * F2; j += blockDim.x) w[j] = W2[j];
    for (int j = threadIdx.x; j < F1; j += blockDim.x) bb[j] = b1[j];
    __syncthreads();
    int t = blockIdx.x * blockDim.x + threadIdx.x;
    int v = t >> 3;
    int q = t & 7;
    if (v >= N) return;
    const uint2* gbase = reinterpret_cast<const uint2*>(g1) + q;   // row = 8 uint2
    uint2 sw = gbase[(size_t)v * 8];                               // self loop g1[v]
    float o0 = bf2f((unsigned short)(sw.x & 0xffff));
    float o1 = bf2f((unsigned short)(sw.x >> 16));
    float o2 = bf2f((unsigned short)(sw.y & 0xffff));
    float o3 = bf2f((unsigned short)(sw.y >> 16));
    int beg = rstart[v];
    int n = cnt[v];
    int n8 = n & ~7;
    for (int j = 0; j < n8; j += 8) {
        int idx = esrc[beg + j + q];       // 8 distinct edges across the group
#pragma unroll
        for (int u = 0; u < 8; ++u) {
            int s = __shfl(idx, u, 8);
            uint2 a = gbase[(size_t)s * 8];
            o0 += bf2f((unsigned short)(a.x & 0xffff));
            o1 += bf2f((unsigned short)(a.x >> 16));
            o2 += bf2f((unsigned short)(a.y & 0xffff));
            o3 += bf2f((unsigned short)(a.y >> 16));
        }
    }
    for (int j = n8; j < n; ++j) {         // tail: uniform load
        int s = esrc[beg + j];
        uint2 a = gbase[(size_t)s * 8];
        o0 += bf2f((unsigned short)(a.x & 0xffff));
        o1 += bf2f((unsigned short)(a.x >> 16));
        o2 += bf2f((unsigned short)(a.y & 0xffff));
        o3 += bf2f((unsigned short)(a.y >> 16));
    }
    float d = dis[v];
    float p0 = 0.0f, p1 = 0.0f;
    float oz[4] = { o0, o1, o2, o3 };
#pragma unroll
    for (int u = 0; u < 4; ++u) {
        int f = q * 4 + u;
        float r = fmaxf(fmaf(d, oz[u], bb[f]), 0.0f);
        p0 = fmaf(r, w[f * F2 + 0], p0);
        p1 = fmaf(r, w[f * F2 + 1], p1);
    }
#pragma unroll
    for (int off = 1; off < 8; off <<= 1) {
        p0 += __shfl_xor(p0, off);
        p1 += __shfl_xor(p1, off);
    }
    if (q == 0) {
        g2[(size_t)v * F2 + 0] = d * p0;
        g2[(size_t)v * F2 + 1] = d * p1;
    }
}

// fused layer2 aggregate + output: 4 lanes per node, strided edges, 4x unroll
__global__ void k_out2(const float* __restrict__ g2, const int* __restrict__ cnt,
                       const int* __restrict__ rstart, const int* __restrict__ esrc,
                       const float* __restrict__ dis, const float* __restrict__ b2,
                       float* __restrict__ out, int N) {
    int t = blockIdx.x * blockDim.x + threadIdx.x;
    int v = t >> 2;
    int l = t & 3;
    if (v >= N) return;
    float o0 = 0.0f, o1 = 0.0f;
    int beg = rstart[v];
    int end = beg + cnt[v];
    int j = beg + l;
    for (; j + 12 < end; j += 16) {        // 4 independent gathers in flight
        int s0 = esrc[j];
        int s1 = esrc[j + 4];
        int s2 = esrc[j + 8];
        int s3 = esrc[j + 12];
        float2 a0 = *reinterpret_cast<const float2*>(g2 + (size_t)s0 * F2);
        float2 a1 = *reinterpret_cast<const float2*>(g2 + (size_t)s1 * F2);
        float2 a2 = *reinterpret_cast<const float2*>(g2 + (size_t)s2 * F2);
        float2 a3 = *reinterpret_cast<const float2*>(g2 + (size_t)s3 * F2);
        o0 += a0.x + a1.x + a2.x + a3.x;
        o1 += a0.y + a1.y + a2.y + a3.y;
    }
    for (; j < end; j += 4) {
        int s = esrc[j];
        const float2 a = *reinterpret_cast<const float2*>(g2 + (size_t)s * F2);
        o0 += a.x; o1 += a.y;
    }
#pragma unroll
    for (int off = 1; off < 4; off <<= 1) {
        o0 += __shfl_xor(o0, off);
        o1 += __shfl_xor(o1, off);
    }
    if (l == 0) {
        float d = dis[v];
        const float2 self = *reinterpret_cast<const float2*>(g2 + (size_t)v * F2);
        out[(size_t)v * F2 + 0] = fmaf(d, o0 + self.x, b2[0]);
        out[(size_t)v * F2 + 1] = fmaf(d, o1 + self.y, b2[1]);
    }
}

extern "C" void kernel_launch(void* const* d_in, const int* in_sizes, int n_in,
                              void* d_out, int out_size, void* d_ws, size_t ws_size,
                              hipStream_t stream) {
    const float* x  = (const float*)d_in[0];
    const int* ei   = (const int*)d_in[1];
    const float* W1 = (const float*)d_in[2];
    const float* b1 = (const float*)d_in[3];
    const float* W2 = (const float*)d_in[4];
    const float* b2 = (const float*)d_in[5];
    float* out = (float*)d_out;

    const int N = in_sizes[0] / F0;          // 100000
    const int E = in_sizes[1] / 2;           // 3200000
    const int* src = ei;
    const int* dst = ei + E;
    const int nb = (N + BMSK) >> BSH;        // 196 buckets of 512 nodes
    const int nchunk = (E + EPB - 1) / EPB;  // 391 chunks
    const size_t pairs_cap = (size_t)E + (size_t)nchunk * nb * 16;  // padded capacity

    // workspace layout (4-byte units; keep pairs offset multiple of 4 for uint4)
    char* wsb = (char*)d_ws;
    unsigned int* btot  = (unsigned int*)wsb;                 // MAXNB*BPAD (4096)
    unsigned int* bfill = btot + MAXNB * BPAD;                // MAXNB*BPAD (4096)
    unsigned int* ecur  = bfill + MAXNB * BPAD;               // 16 (line pad)
    int* bbase          = (int*)(ecur + 16);                  // MAXNB+4 (pad to x4)
    int* cnt            = bbase + MAXNB + 4;                  // N
    float* dis          = (float*)(cnt + N);                  // N
    int* rstart         = (int*)(dis + N);                    // N
    unsigned int* pairs = (unsigned int*)(rstart + N);        // pairs_cap (16B-aligned)
    int* esrc           = (int*)(pairs + pairs_cap);          // E
    unsigned short* g1  = (unsigned short*)(esrc + E);        // 32N ushort
    float* g2           = (float*)(g1 + (size_t)32 * N);      // 2N

    hipMemsetAsync(btot, 0, ((size_t)2 * MAXNB * BPAD + 16) * sizeof(int), stream);

    const int B = 256;
    k_bhist<<<nchunk, 512, 0, stream>>>(dst, btot, E, nb);
    k_bscan<<<1, MAXNB, 0, stream>>>(btot, bbase, bfill, nb);
    k_binA<<<nchunk, 512, 0, stream>>>(src, dst, bfill, pairs, E, nb);
    k_binB<<<nb, 512, 0, stream>>>(pairs, bbase, ecur, cnt, dis, rstart, esrc, N);
    k_g1<<<(N + B - 1) / B, B, 0, stream>>>(x, W1, dis, g1, N);
    k_layer1<<<(N * 8 + B - 1) / B, B, 0, stream>>>(g1, cnt, rstart, esrc, dis, b1, W2, g2, N);
    k_out2<<<(N * 4 + B - 1) / B, B, 0, stream>>>(g2, cnt, rstart, esrc, dis, b2, out, N);
}

// Round 9
// 141.686 us; speedup vs baseline: 5.7314x; 1.1609x over previous
//
#include <hip/hip_runtime.h>

// GCN 2-layer via two-level counting-sort CSR + gather-sum (no float atomics).
// Layer1 aggregates BEFORE the GEMM (linearity): y[v] = sum xd[u] + xd[v],
// xd = bf16(dis*x) -> 32B rows, 3.2MB table (L2-resident per XCD).
// Then per-node MLP: z=relu(dis*(y@W1)+b1); g2=dis*(z@W2), fused in-kernel.

static constexpr int F0 = 16;
static constexpr int F1 = 32;
static constexpr int F2 = 2;
static constexpr int BSH   = 9;     // bucket = dst>>9 (512 nodes/bucket)
static constexpr int BMSK  = 511;
static constexpr int MAXNB = 256;   // max coarse buckets (N<=131072)
static constexpr int BPAD  = 16;    // pad global counters to own 64B line
static constexpr int EPB   = 8192;  // edges per binA/bhist chunk (same!)
static constexpr int SORTCAP = EPB + MAXNB * 16;   // 12288 slots
static constexpr unsigned SENT = 0xFFFFFFFFu;

__device__ inline unsigned roundup16(unsigned h) { return (h + 15u) & ~15u; }

__device__ inline unsigned f2bf(float f) {
    unsigned u = __float_as_uint(f);
    return (u + 0x7fffu + ((u >> 16) & 1u)) >> 16;   // RNE
}
__device__ inline float bf2f(unsigned b) {
    return __uint_as_float(b << 16);
}

// per-chunk bucket histogram; accumulates PADDED per-chunk totals
__global__ __launch_bounds__(512) void k_bhist(const int* __restrict__ dst,
                                               unsigned int* __restrict__ btot,
                                               int E, int nb) {
    __shared__ unsigned int h[MAXNB];
    for (int b = threadIdx.x; b < MAXNB; b += blockDim.x) h[b] = 0;
    __syncthreads();
    int e0 = blockIdx.x * EPB;
    int e1 = min(e0 + EPB, E);
    for (int e = e0 + (int)threadIdx.x; e < e1; e += blockDim.x)
        atomicAdd(&h[((unsigned)dst[e]) >> BSH], 1u);
    __syncthreads();
    for (int b = threadIdx.x; b < nb; b += blockDim.x)
        if (h[b]) atomicAdd(&btot[b * BPAD], roundup16(h[b]));
}

// single block of MAXNB threads: exclusive scan of padded bucket totals
__global__ void k_bscan(const unsigned int* __restrict__ btot, int* __restrict__ bbase,
                        unsigned int* __restrict__ bfill, int nb) {
    __shared__ int s[MAXNB];
    int tid = threadIdx.x;
    int v = (tid < nb) ? (int)btot[tid * BPAD] : 0;
    s[tid] = v;
    __syncthreads();
    for (int off = 1; off < MAXNB; off <<= 1) {
        int t = (tid >= off) ? s[tid - off] : 0;
        __syncthreads();
        s[tid] += t;
        __syncthreads();
    }
    if (tid < nb) {
        int ex = s[tid] - v;
        bbase[tid] = ex;
        bfill[tid * BPAD] = (unsigned)ex;
    }
    if (tid == nb - 1) bbase[nb] = s[tid];   // padded grand total
}

// LDS counting sort of the chunk, then per-bucket wave burst copy to global
__global__ __launch_bounds__(512) void k_binA(const int* __restrict__ src,
                                              const int* __restrict__ dst,
                                              unsigned int* __restrict__ bfill,
                                              unsigned int* __restrict__ pairs,
                                              int E, int nb) {
    __shared__ unsigned int h[MAXNB];
    __shared__ unsigned int lbase[MAXNB];
    __shared__ unsigned int bs[MAXNB];
    __shared__ unsigned int cur[MAXNB];
    __shared__ __attribute__((aligned(16))) unsigned int sorted[SORTCAP];
    int tid = threadIdx.x;
    for (int b = tid; b < MAXNB; b += 512) { h[b] = 0; cur[b] = 0; }
    for (int i = tid; i < SORTCAP; i += 512) sorted[i] = SENT;
    __syncthreads();
    int e0 = blockIdx.x * EPB;
    int e1 = min(e0 + EPB, E);
    for (int e = e0 + tid; e < e1; e += 512)
        atomicAdd(&h[((unsigned)dst[e]) >> BSH], 1u);
    __syncthreads();
    if (tid < MAXNB) lbase[tid] = roundup16(h[tid]);
    __syncthreads();
    for (int off = 1; off < MAXNB; off <<= 1) {
        unsigned t = (tid >= off && tid < MAXNB) ? lbase[tid - off] : 0u;
        __syncthreads();
        if (tid < MAXNB) lbase[tid] += t;
        __syncthreads();
    }
    if (tid < MAXNB) lbase[tid] -= roundup16(h[tid]);   // exclusive
    if (tid < nb && h[tid]) bs[tid] = atomicAdd(&bfill[tid * BPAD], roundup16(h[tid]));
    __syncthreads();
    for (int e = e0 + tid; e < e1; e += 512) {
        unsigned d = (unsigned)dst[e];
        unsigned b = d >> BSH;
        unsigned pos = lbase[b] + atomicAdd(&cur[b], 1u);
        sorted[pos] = (((unsigned)src[e]) << BSH) | (d & BMSK);
    }
    __syncthreads();
    int wid = tid >> 6;
    int lane = tid & 63;
    for (int b = wid; b < nb; b += 8) {
        unsigned np = roundup16(h[b]) >> 2;   // uint4 count
        if (!np) continue;
        const uint4* sp = reinterpret_cast<const uint4*>(&sorted[lbase[b]]);
        uint4* gp = reinterpret_cast<uint4*>(&pairs[bs[b]]);
        for (unsigned k = lane; k < np; k += 64) gp[k] = sp[k];
    }
}

// one block (512 threads) per bucket: node hist + scan -> cnt/dis/rstart,
// compact scatter of src into esrc via global cursor
__global__ __launch_bounds__(512) void k_binB(const unsigned int* __restrict__ pairs,
                                              const int* __restrict__ bbase,
                                              unsigned int* __restrict__ ecur,
                                              int* __restrict__ cnt, float* __restrict__ dis,
                                              int* __restrict__ rstart, int* __restrict__ esrc,
                                              int N) {
    __shared__ unsigned int h[512];
    __shared__ int sc[512];
    __shared__ unsigned int cur[512];
    __shared__ int base;
    int tid = threadIdx.x;
    int b = blockIdx.x;
    int node0 = b << BSH;
    h[tid] = 0;
    cur[tid] = 0;
    __syncthreads();
    int r0 = bbase[b], r1 = bbase[b + 1];
    for (int i = r0 + tid; i < r1; i += 512) {
        unsigned p = pairs[i];
        if (p != SENT) atomicAdd(&h[p & BMSK], 1u);
    }
    __syncthreads();
    int v = (int)h[tid];
    sc[tid] = v;
    __syncthreads();
    for (int off = 1; off < 512; off <<= 1) {
        int t = (tid >= off) ? sc[tid - off] : 0;
        __syncthreads();
        sc[tid] += t;
        __syncthreads();
    }
    int ex = sc[tid] - v;
    __syncthreads();
    sc[tid] = ex;
    if (tid == 511) base = (int)atomicAdd(ecur, (unsigned)(ex + v));
    __syncthreads();
    int node = node0 + tid;
    if (node < N) {
        cnt[node] = v;
        dis[node] = rsqrtf((float)(v + 1));
        rstart[node] = base + ex;
    }
    for (int i = r0 + tid; i < r1; i += 512) {
        unsigned p = pairs[i];
        if (p == SENT) continue;
        unsigned l = p & BMSK;
        unsigned off = atomicAdd(&cur[l], 1u);
        esrc[base + sc[l] + (int)off] = (int)(p >> BSH);
    }
}

// xd[i,:] = bf16( dis[i] * x[i,:] )  (16 bf16 = 32B row = 8 u32)
__global__ void k_xd(const float* __restrict__ x, const float* __restrict__ dis,
                     unsigned* __restrict__ xd, int N) {
    int i = blockIdx.x * blockDim.x + threadIdx.x;
    if (i >= N) return;
    float d = dis[i];
    const float4* xp = reinterpret_cast<const float4*>(x + (size_t)i * F0);
    unsigned pk[8];
#pragma unroll
    for (int q = 0; q < 4; ++q) {
        float4 v = xp[q];
        pk[2 * q + 0] = f2bf(d * v.x) | (f2bf(d * v.y) << 16);
        pk[2 * q + 1] = f2bf(d * v.z) | (f2bf(d * v.w) << 16);
    }
    uint4* o = reinterpret_cast<uint4*>(xd + (size_t)i * 8);
    o[0] = make_uint4(pk[0], pk[1], pk[2], pk[3]);
    o[1] = make_uint4(pk[4], pk[5], pk[6], pk[7]);
}

// fused layer1: aggregate xd rows (32B, L2-resident table) then per-node MLP.
// 8 lanes/node, 4B (2 bf16 features) each; y exchanged via wave-local LDS.
__global__ void k_layer1(const unsigned* __restrict__ xd, const int* __restrict__ cnt,
                         const int* __restrict__ rstart, const int* __restrict__ esrc,
                         const float* __restrict__ dis, const float* __restrict__ b1,
                         const float* __restrict__ W1, const float* __restrict__ W2,
                         float* __restrict__ g2, int N) {
    __shared__ float w1[F0 * F1];
    __shared__ float w2[F1 * F2];
    __shared__ float bb[F1];
    __shared__ float ymat[32][17];   // 32 nodes/block, +1 pad
    for (int j = threadIdx.x; j < F0 * F1; j += blockDim.x) w1[j] = W1[j];
    for (int j = threadIdx.x; j < F1 * F2; j += blockDim.x) w2[j] = W2[j];
    for (int j = threadIdx.x; j < F1; j += blockDim.x) bb[j] = b1[j];
    __syncthreads();
    int t = blockIdx.x * blockDim.x + threadIdx.x;
    int v = t >> 3;
    int q = t & 7;
    if (v >= N) return;
    const unsigned* base = xd + q;             // row stride 8 u32
    unsigned sw = base[(size_t)v * 8];         // self loop xd[v]
    float a0 = bf2f(sw & 0xffffu);
    float a1 = bf2f(sw >> 16);
    int beg = rstart[v];
    int n = cnt[v];
    int n8 = n & ~7;
    for (int j = 0; j < n8; j += 8) {
        int idx = esrc[beg + j + q];           // 8 distinct edges across group
#pragma unroll
        for (int u = 0; u < 8; ++u) {
            int s = __shfl(idx, u, 8);
            unsigned a = base[(size_t)s * 8];
            a0 += bf2f(a & 0xffffu);
            a1 += bf2f(a >> 16);
        }
    }
    for (int j = n8; j < n; ++j) {             // tail: uniform load
        int s = esrc[beg + j];
        unsigned a = base[(size_t)s * 8];
        a0 += bf2f(a & 0xffffu);
        a1 += bf2f(a >> 16);
    }
    // exchange y within the 8-lane group (wave-local LDS, lockstep -> no sync)
    int ln = threadIdx.x >> 3;
    ymat[ln][2 * q + 0] = a0;
    ymat[ln][2 * q + 1] = a1;
    float y[F0];
#pragma unroll
    for (int k = 0; k < F0; ++k) y[k] = ymat[ln][k];
    float d = dis[v];
    float p0 = 0.0f, p1 = 0.0f;
#pragma unroll
    for (int u = 0; u < 4; ++u) {
        int jf = q * 4 + u;                    // 32 features across 8 lanes x 4
        float s = 0.0f;
#pragma unroll
        for (int k = 0; k < F0; ++k) s = fmaf(y[k], w1[k * F1 + jf], s);
        float r = fmaxf(fmaf(d, s, bb[jf]), 0.0f);
        p0 = fmaf(r, w2[jf * F2 + 0], p0);
        p1 = fmaf(r, w2[jf * F2 + 1], p1);
    }
#pragma unroll
    for (int off = 1; off < 8; off <<= 1) {
        p0 += __shfl_xor(p0, off);
        p1 += __shfl_xor(p1, off);
    }
    if (q == 0) {
        g2[(size_t)v * F2 + 0] = d * p0;
        g2[(size_t)v * F2 + 1] = d * p1;
    }
}

// fused layer2 aggregate + output: 4 lanes per node, strided edges, 4x unroll
__global__ void k_out2(const float* __restrict__ g2, const int* __restrict__ cnt,
                       const int* __restrict__ rstart, const int* __restrict__ esrc,
                       const float* __restrict__ dis, const float* __restrict__ b2,
                       float* __restrict__ out, int N) {
    int t = blockIdx.x * blockDim.x + threadIdx.x;
    int v = t >> 2;
    int l = t & 3;
    if (v >= N) return;
    float o0 = 0.0f, o1 = 0.0f;
    int beg = rstart[v];
    int end = beg + cnt[v];
    int j = beg + l;
    for (; j + 12 < end; j += 16) {        // 4 independent gathers in flight
        int s0 = esrc[j];
        int s1 = esrc[j + 4];
        int s2 = esrc[j + 8];
        int s3 = esrc[j + 12];
        float2 a0 = *reinterpret_cast<const float2*>(g2 + (size_t)s0 * F2);
        float2 a1 = *reinterpret_cast<const float2*>(g2 + (size_t)s1 * F2);
        float2 a2 = *reinterpret_cast<const float2*>(g2 + (size_t)s2 * F2);
        float2 a3 = *reinterpret_cast<const float2*>(g2 + (size_t)s3 * F2);
        o0 += a0.x + a1.x + a2.x + a3.x;
        o1 += a0.y + a1.y + a2.y + a3.y;
    }
    for (; j < end; j += 4) {
        int s = esrc[j];
        const float2 a = *reinterpret_cast<const float2*>(g2 + (size_t)s * F2);
        o0 += a.x; o1 += a.y;
    }
#pragma unroll
    for (int off = 1; off < 4; off <<= 1) {
        o0 += __shfl_xor(o0, off);
        o1 += __shfl_xor(o1, off);
    }
    if (l == 0) {
        float d = dis[v];
        const float2 self = *reinterpret_cast<const float2*>(g2 + (size_t)v * F2);
        out[(size_t)v * F2 + 0] = fmaf(d, o0 + self.x, b2[0]);
        out[(size_t)v * F2 + 1] = fmaf(d, o1 + self.y, b2[1]);
    }
}

extern "C" void kernel_launch(void* const* d_in, const int* in_sizes, int n_in,
                              void* d_out, int out_size, void* d_ws, size_t ws_size,
                              hipStream_t stream) {
    const float* x  = (const float*)d_in[0];
    const int* ei   = (const int*)d_in[1];
    const float* W1 = (const float*)d_in[2];
    const float* b1 = (const float*)d_in[3];
    const float* W2 = (const float*)d_in[4];
    const float* b2 = (const float*)d_in[5];
    float* out = (float*)d_out;

    const int N = in_sizes[0] / F0;          // 100000
    const int E = in_sizes[1] / 2;           // 3200000
    const int* src = ei;
    const int* dst = ei + E;
    const int nb = (N + BMSK) >> BSH;        // 196 buckets of 512 nodes
    const int nchunk = (E + EPB - 1) / EPB;  // 391 chunks
    const size_t pairs_cap = (size_t)E + (size_t)nchunk * nb * 16;  // padded capacity

    // workspace layout (4-byte units; keep pairs/xd 16B-aligned)
    char* wsb = (char*)d_ws;
    unsigned int* btot  = (unsigned int*)wsb;                 // MAXNB*BPAD (4096)
    unsigned int* bfill = btot + MAXNB * BPAD;                // MAXNB*BPAD (4096)
    unsigned int* ecur  = bfill + MAXNB * BPAD;               // 16 (line pad)
    int* bbase          = (int*)(ecur + 16);                  // MAXNB+4 (pad to x4)
    int* cnt            = bbase + MAXNB + 4;                  // N
    float* dis          = (float*)(cnt + N);                  // N
    int* rstart         = (int*)(dis + N);                    // N
    unsigned int* pairs = (unsigned int*)(rstart + N);        // pairs_cap
    int* esrc           = (int*)(pairs + pairs_cap);          // E
    unsigned* xd        = (unsigned*)(esrc + E);              // 8N u32 (32B rows)
    float* g2           = (float*)(xd + (size_t)8 * N);       // 2N

    hipMemsetAsync(btot, 0, ((size_t)2 * MAXNB * BPAD + 16) * sizeof(int), stream);

    const int B = 256;
    k_bhist<<<nchunk, 512, 0, stream>>>(dst, btot, E, nb);
    k_bscan<<<1, MAXNB, 0, stream>>>(btot, bbase, bfill, nb);
    k_binA<<<nchunk, 512, 0, stream>>>(src, dst, bfill, pairs, E, nb);
    k_binB<<<nb, 512, 0, stream>>>(pairs, bbase, ecur, cnt, dis, rstart, esrc, N);
    k_xd<<<(N + B - 1) / B, B, 0, stream>>>(x, dis, xd, N);
    k_layer1<<<(N * 8 + B - 1) / B, B, 0, stream>>>(xd, cnt, rstart, esrc, dis, b1, W1, W2, g2, N);
    k_out2<<<(N * 4 + B - 1) / B, B, 0, stream>>>(g2, cnt, rstart, esrc, dis, b2, out, N);
}